// Round 5
// baseline (245.979 us; speedup 1.0000x reference)
//
#include <hip/hip_runtime.h>

#define B_   4
#define N_   2048
#define DIM  128
#define NH   8
#define HD   16
#define FFN_ 256
#define LN_EPS 1e-5f
#define BN   (B_*N_)
#define LOG2E 1.44269504f
#define RESCALE_THR 12.0f   // log2 units

#if __has_builtin(__builtin_amdgcn_exp2f)
#define EXP2(x) __builtin_amdgcn_exp2f(x)
#else
#define EXP2(x) exp2f(x)
#endif

typedef __bf16 bf16x8 __attribute__((ext_vector_type(8)));
typedef short  s16x8  __attribute__((ext_vector_type(8)));
typedef float  f32x16 __attribute__((ext_vector_type(16)));
typedef unsigned int u32x4 __attribute__((ext_vector_type(4)));

// ROCm clang declares __builtin_amdgcn_mfma_f32_32x32x16_bf16 with either
// <8 x bf16> or <8 x i16> operands depending on version. SFINAE both.
template<class T> struct as_short_vec { using type = s16x8; };

template <class T>
__device__ auto mfma_try(T a, T b, f32x16 c, int)
    -> decltype(__builtin_amdgcn_mfma_f32_32x32x16_bf16(a, b, c, 0, 0, 0)) {
  return __builtin_amdgcn_mfma_f32_32x32x16_bf16(a, b, c, 0, 0, 0);
}
template <class T>
__device__ f32x16 mfma_try(T a, T b, f32x16 c, long) {
  return __builtin_amdgcn_mfma_f32_32x32x16_bf16(
      __builtin_bit_cast(typename as_short_vec<T>::type, a),
      __builtin_bit_cast(typename as_short_vec<T>::type, b), c, 0, 0, 0);
}
__device__ __forceinline__ f32x16 mfma_bf(bf16x8 a, bf16x8 b, f32x16 c) {
  return mfma_try(a, b, c, 0);
}

// ---------------- adj (int32 0/1) -> 64-bit masks ----------------
__global__ __launch_bounds__(256) void k_adjbits(const int* __restrict__ adj,
                                                 unsigned long long* __restrict__ bits) {
    long long idx = (long long)blockIdx.x * 256 + threadIdx.x;
    int v = adj[idx] != 0;
    unsigned long long m = __ballot(v);
    if ((threadIdx.x & 63) == 0) bits[idx >> 6] = m;
}

// ------- expand adj bits into MFMA-fragment-ordered 16-bit AND masks -------
// Mex[((tg*2048+q)*2+hi)*8 + j] : u32 whose low/high 16 bits are 0xFFFF iff
// keys pos(2j),pos(2j+1) of tile tg are unmasked for query q,
// pos(r) = (r&3) + 8*(r>>2) + 4*hi.
__global__ __launch_bounds__(256) void k_adjexp(
    const unsigned long long* __restrict__ adjb, unsigned int* __restrict__ Mex) {
    const int g  = blockIdx.x * 256 + threadIdx.x;   // 64*2048*2 threads
    const int hi = g & 1;
    const int q  = (g >> 1) & 2047;
    const int tg = g >> 12;
    unsigned long long w = adjb[(size_t)q * 32 + (tg >> 1)];
    unsigned mm = (unsigned)(w >> ((tg & 1) * 32));
    const int pbase[8] = {0, 2, 8, 10, 16, 18, 24, 26};
    unsigned int out[8];
    #pragma unroll
    for (int j = 0; j < 8; ++j) {
        int base = pbase[j] + 4 * hi;
        unsigned lo = (mm >> base) & 1u;
        unsigned hb = (mm >> (base + 1)) & 1u;
        out[j] = (lo ? 0xFFFFu : 0u) | (hb ? 0xFFFF0000u : 0u);
    }
    unsigned int* dst = Mex + (size_t)g * 8;
    *(u32x4*)dst       = u32x4{out[0], out[1], out[2], out[3]};
    *(u32x4*)(dst + 4) = u32x4{out[4], out[5], out[6], out[7]};
}

// ---------------- fused QKV projection -> bf16, attention layouts ----------
// Qb,Kb: [B][H][N][HD] bf16 (Q pre-scaled by 0.25*log2e);
// Vt: [B][H][16][N] bf16 = V^T with keys permuted per 32-block.
__global__ __launch_bounds__(512) void k_qkv(const float* __restrict__ h,
    const float* __restrict__ Wq, const float* __restrict__ Wk, const float* __restrict__ Wv,
    __bf16* __restrict__ Qb, __bf16* __restrict__ Kb, __bf16* __restrict__ Vt) {
    __shared__ float hs[32][DIM];
    const int r0  = blockIdx.x * 32;
    const int tid = threadIdx.x;
    for (int i = tid; i < 32 * DIM; i += 512)
        hs[i >> 7][i & 127] = h[(size_t)r0 * DIM + i];
    __syncthreads();
    const int c     = tid & 127;
    const int rbase = (tid >> 7) * 8;
    float aq[8], ak[8], av[8];
    #pragma unroll
    for (int i = 0; i < 8; ++i) { aq[i] = 0.f; ak[i] = 0.f; av[i] = 0.f; }
    for (int k4 = 0; k4 < DIM; k4 += 4) {
        float4 hv[8];
        #pragma unroll
        for (int r = 0; r < 8; ++r) hv[r] = *(const float4*)&hs[rbase + r][k4];
        #pragma unroll
        for (int kk = 0; kk < 4; ++kk) {
            const int k = k4 + kk;
            float wq = Wq[k * DIM + c], wk = Wk[k * DIM + c], wv = Wv[k * DIM + c];
            #pragma unroll
            for (int r = 0; r < 8; ++r) {
                float hvv = ((const float*)&hv[r])[kk];
                aq[r] += hvv * wq; ak[r] += hvv * wk; av[r] += hvv * wv;
            }
        }
    }
    const int hh = c >> 4, d = c & 15;
    const int b  = r0 >> 11;
    const int n0 = (r0 & (N_ - 1)) + rbase;
    size_t qk = ((size_t)(b * NH + hh) * N_ + n0) * HD + d;
    size_t vh = ((size_t)(b * NH + hh) * HD + d) * N_;
    #pragma unroll
    for (int i = 0; i < 8; ++i) {
        Qb[qk + (size_t)i * HD] = (__bf16)(aq[i] * (0.25f * LOG2E));
        Kb[qk + (size_t)i * HD] = (__bf16)ak[i];
        int n  = n0 + i;
        int g  = (n >> 2) & 7;
        int ng = (g & 4) | ((g & 1) << 1) | ((g >> 1) & 1);
        Vt[vh + ((n & ~31) | (ng << 2) | (n & 3))] = (__bf16)av[i];
    }
}

// ---------------- masked flash attention, MFMA 32x32x16, 4-way split-K ----
// grid: B*H*(N/64) = 1024 blocks x 512 thr (8 waves).
// wave wv: wq = wv&1 (q sub-tile of 32 rows), kq = wv>>1 (K quarter, 512 keys).
__global__ __launch_bounds__(512, 8) void k_attn(
    const __bf16* __restrict__ Qb, const __bf16* __restrict__ Kb,
    const __bf16* __restrict__ Vt, const unsigned int* __restrict__ Mex,
    float* __restrict__ AO) {
    const int bid  = blockIdx.x;
    const int qt   = bid & 31;          // N/64 = 32 q-tiles
    const int hh   = (bid >> 5) & 7;
    const int b    = bid >> 8;
    const int wv   = threadIdx.x >> 6;
    const int wq   = wv & 1;
    const int kq   = wv >> 1;
    const int lane = threadIdx.x & 63;
    const int l31  = lane & 31, hi = lane >> 5;
    const int q     = qt * 64 + wq * 32 + l31;
    const int kbase = kq * 512;
    const int NT    = 16;               // 16 tiles of 32 keys per quarter

    __shared__ float accL[3][2][64][9];
    __shared__ float mL[4][2][32], sL[4][2][32];

    const __bf16* Qh = Qb + (size_t)(b * NH + hh) * N_ * HD;
    const __bf16* Kh = Kb + (size_t)(b * NH + hh) * N_ * HD;
    const __bf16* Vh = Vt + ((size_t)(b * NH + hh) * HD + (l31 & 15)) * N_;
    const bool vload = (l31 < 16);
    const bf16x8 ones8 = __builtin_bit_cast(bf16x8,
        u32x4{0x3F803F80u, 0x3F803F80u, 0x3F803F80u, 0x3F803F80u});

    // Q^T B-frag: col q = l31, d = hi*8 + i — one 16B load.
    bf16x8 qf = *(const bf16x8*)(Qh + (size_t)q * HD + hi * 8);

    f32x16 acc;
    #pragma unroll
    for (int i = 0; i < 16; ++i) acc[i] = 0.f;
    float m = -1e30f;
    const f32x16 z = {};

    const unsigned int* Mp =
        Mex + ((size_t)(kq * NT) * 4096 + (size_t)q * 2 + hi) * 8;

    bf16x8 kf  = *(const bf16x8*)(Kh + (size_t)(kbase + l31) * HD + hi * 8);
    bf16x8 vfa = vload ? *(const bf16x8*)(Vh + kbase + hi * 8)      : ones8;
    bf16x8 vfb = vload ? *(const bf16x8*)(Vh + kbase + 16 + hi * 8) : ones8;
    u32x4  ma  = *(const u32x4*)Mp;
    u32x4  mb  = *(const u32x4*)(Mp + 4);

    for (int t = 0; t < NT; ++t) {
        // prefetch tile t+1
        bf16x8 kf_n = kf, vfa_n = vfa, vfb_n = vfb;
        u32x4 ma_n = ma, mb_n = mb;
        if (t + 1 < NT) {
            const int k1 = kbase + (t + 1) * 32;
            kf_n = *(const bf16x8*)(Kh + (size_t)(k1 + l31) * HD + hi * 8);
            if (vload) {
                vfa_n = *(const bf16x8*)(Vh + k1 + hi * 8);
                vfb_n = *(const bf16x8*)(Vh + k1 + 16 + hi * 8);
            }
            const unsigned int* Mq = Mp + 32768;
            ma_n = *(const u32x4*)Mq;
            mb_n = *(const u32x4*)(Mq + 4);
        }

        // S^T[k][q] (log2-scaled): D: q = l31, k = (r&3)+8*(r>>2)+4*hi
        f32x16 st = mfma_bf(kf, qf, z);

        // local (lane-half) tile max over raw scores
        float a0 = fmaxf(fmaxf(st[0], st[1]), st[2]);
        float a1 = fmaxf(fmaxf(st[3], st[4]), st[5]);
        float a2 = fmaxf(fmaxf(st[6], st[7]), st[8]);
        float a3 = fmaxf(fmaxf(st[9], st[10]), st[11]);
        float a4 = fmaxf(fmaxf(st[12], st[13]), st[14]);
        float b0 = fmaxf(fmaxf(a0, a1), a2);
        float b1 = fmaxf(fmaxf(a3, a4), st[15]);
        float tm = fmaxf(b0, b1);

        // deferred rescale; cross-half agreement only inside the rare branch.
        // Invariant after: st - m <= THR for every lane (by __any over 64 lanes).
        if (__any(tm > m + RESCALE_THR)) {
            float tmj = fmaxf(tm, __shfl_xor(tm, 32));
            float mn  = fmaxf(m, tmj);
            float sc  = EXP2(m - mn);
            #pragma unroll
            for (int r = 0; r < 9; ++r) acc[r] *= sc;
            m = mn;
        }

        // p = 2^(st - m) <= 2^12; mask applied on packed bf16 via AND
        float p[16];
        #pragma unroll
        for (int r = 0; r < 16; ++r) p[r] = EXP2(st[r] - m);
        bf16x8 pa, pb;
        #pragma unroll
        for (int r = 0; r < 8; ++r) { pa[r] = (__bf16)p[r]; pb[r] = (__bf16)p[r + 8]; }
        pa = __builtin_bit_cast(bf16x8, __builtin_bit_cast(u32x4, pa) & ma);
        pb = __builtin_bit_cast(bf16x8, __builtin_bit_cast(u32x4, pb) & mb);

        // PV; A rows 16..31 are register-ones -> acc[8] accumulates sum(p)
        acc = mfma_bf(vfa, pa, acc);
        acc = mfma_bf(vfb, pb, acc);

        kf = kf_n; vfa = vfa_n; vfb = vfb_n; ma = ma_n; mb = mb_n;
        Mp += 32768;
    }

    const float sum = acc[8];

    // ---- 4-way split-K merge through LDS ----
    if (kq != 0) {
        #pragma unroll
        for (int r = 0; r < 8; ++r) accL[kq - 1][wq][lane][r] = acc[r];
    }
    if (hi == 0) { mL[kq][wq][l31] = m; sL[kq][wq][l31] = sum; }
    __syncthreads();
    if (kq == 0) {
        float M = m;
        #pragma unroll
        for (int i = 1; i < 4; ++i) M = fmaxf(M, mL[i][wq][l31]);
        float e0 = EXP2(m - M);
        float s  = sum * e0;
        float e[3];
        #pragma unroll
        for (int i = 0; i < 3; ++i) {
            e[i] = EXP2(mL[i + 1][wq][l31] - M);
            s += sL[i + 1][wq][l31] * e[i];
        }
        float inv = 1.f / s;
        float o[8];
        #pragma unroll
        for (int r = 0; r < 8; ++r) {
            float v = acc[r] * e0;
            #pragma unroll
            for (int i = 0; i < 3; ++i) v += accL[i][wq][lane][r] * e[i];
            o[r] = v * inv;
        }
        float* op = AO + ((size_t)(b * N_ + q)) * DIM + hh * HD + 4 * hi;
        float4 o0 = { o[0], o[1], o[2], o[3] };
        float4 o1 = { o[4], o[5], o[6], o[7] };
        *(float4*)op       = o0;   // d = 4*hi + 0..3
        *(float4*)(op + 8) = o1;   // d = 8 + 4*hi + 0..3
    }
}

// ---------------- Wo projection + residual + LN1 ----------------
// 16 rows/block, 256 threads, grid BN/16.
__global__ __launch_bounds__(256) void k_proj_ln(
    const float* __restrict__ AO, const float* __restrict__ h,
    const float* __restrict__ Wo, const float* __restrict__ bo,
    const float* __restrict__ g, const float* __restrict__ bln,
    float* __restrict__ X) {
    const int r0  = blockIdx.x * 16;
    const int tid = threadIdx.x;
    __shared__ float a[16][DIM];
    __shared__ float vv[16][DIM];
    __shared__ float mu_s[16], rs_s[16];
    for (int i = tid; i < 16 * DIM; i += 256)
        a[i >> 7][i & 127] = AO[(size_t)r0 * DIM + i];
    __syncthreads();
    const int c = tid & 127, rg = tid >> 7;
    float accv[8];
    float bov = bo[c];
    #pragma unroll
    for (int r = 0; r < 8; ++r) accv[r] = bov;
    for (int k = 0; k < DIM; ++k) {
        float w = Wo[k * DIM + c];
        #pragma unroll
        for (int r = 0; r < 8; ++r) accv[r] += a[rg * 8 + r][k] * w;
    }
    #pragma unroll
    for (int r = 0; r < 8; ++r)
        vv[rg * 8 + r][c] = accv[r] + h[((size_t)(r0 + rg * 8 + r)) * DIM + c];
    __syncthreads();
    const int wvx = tid >> 6, ln = tid & 63;
    #pragma unroll
    for (int i = 0; i < 4; ++i) {
        int r = wvx * 4 + i;
        float x0 = vv[r][ln], x1 = vv[r][ln + 64];
        float s = x0 + x1, s2 = x0 * x0 + x1 * x1;
        for (int off = 1; off < 64; off <<= 1) {
            s  += __shfl_xor(s,  off);
            s2 += __shfl_xor(s2, off);
        }
        if (ln == 0) {
            float mu = s * (1.f / DIM);
            float var = s2 * (1.f / DIM) - mu * mu;
            mu_s[r] = mu; rs_s[r] = rsqrtf(var + LN_EPS);
        }
    }
    __syncthreads();
    float gc = g[c], bc = bln[c];
    #pragma unroll
    for (int r = 0; r < 8; ++r) {
        int rr = rg * 8 + r;
        X[((size_t)(r0 + rr)) * DIM + c] = (vv[rr][c] - mu_s[rr]) * rs_s[rr] * gc + bc;
    }
}

// ---------------- FFN + residual + LN2 ----------------
// 16 rows/block, 256 threads, grid BN/16.
__global__ __launch_bounds__(256) void k_ffn_ln(
    const float* __restrict__ X,
    const float* __restrict__ W1, const float* __restrict__ b1,
    const float* __restrict__ W2, const float* __restrict__ b2,
    const float* __restrict__ g, const float* __restrict__ bln,
    float* __restrict__ out) {
    const int r0  = blockIdx.x * 16;
    const int tid = threadIdx.x;
    __shared__ float xs[16][DIM];
    __shared__ float ts[16][FFN_];
    __shared__ float vv[16][DIM];
    __shared__ float mu_s[16], rs_s[16];
    for (int i = tid; i < 16 * DIM; i += 256)
        xs[i >> 7][i & 127] = X[(size_t)r0 * DIM + i];
    __syncthreads();
    {
        float accv[16];
        float bb = b1[tid];
        #pragma unroll
        for (int r = 0; r < 16; ++r) accv[r] = bb;
        for (int k = 0; k < DIM; ++k) {
            float w = W1[k * FFN_ + tid];
            #pragma unroll
            for (int r = 0; r < 16; ++r) accv[r] += xs[r][k] * w;
        }
        #pragma unroll
        for (int r = 0; r < 16; ++r) ts[r][tid] = fmaxf(accv[r], 0.f);
    }
    __syncthreads();
    {
        const int c = tid & 127, rg = tid >> 7;
        float y[8];
        float bb = b2[c];
        #pragma unroll
        for (int i = 0; i < 8; ++i) y[i] = bb;
        for (int k = 0; k < FFN_; ++k) {
            float w = W2[k * DIM + c];
            #pragma unroll
            for (int i = 0; i < 8; ++i) y[i] += ts[rg * 8 + i][k] * w;
        }
        #pragma unroll
        for (int i = 0; i < 8; ++i)
            vv[rg * 8 + i][c] = y[i] + xs[rg * 8 + i][c];
    }
    __syncthreads();
    {
        const int wvx = tid >> 6, ln = tid & 63;
        #pragma unroll
        for (int i = 0; i < 4; ++i) {
            int rr = wvx * 4 + i;
            float x0 = vv[rr][ln], x1 = vv[rr][ln + 64];
            float s = x0 + x1, s2 = x0 * x0 + x1 * x1;
            for (int off = 1; off < 64; off <<= 1) {
                s  += __shfl_xor(s,  off);
                s2 += __shfl_xor(s2, off);
            }
            if (ln == 0) {
                float mu = s * (1.f / DIM);
                float var = s2 * (1.f / DIM) - mu * mu;
                mu_s[rr] = mu; rs_s[rr] = rsqrtf(var + LN_EPS);
            }
        }
    }
    __syncthreads();
    {
        const int c = tid & 127, rg = tid >> 7;
        float gc = g[c], bc = bln[c];
        #pragma unroll
        for (int i = 0; i < 8; ++i) {
            int rr = rg * 8 + i;
            out[((size_t)(r0 + rr)) * DIM + c] =
                (vv[rr][c] - mu_s[rr]) * rs_s[rr] * gc + bc;
        }
    }
}

extern "C" void kernel_launch(void* const* d_in, const int* in_sizes, int n_in,
                              void* d_out, int out_size, void* d_ws, size_t ws_size,
                              hipStream_t stream) {
    const int*   adj = (const int*)  d_in[0];
    const float* h   = (const float*)d_in[1];
    const float* Wq  = (const float*)d_in[2];
    const float* Wk  = (const float*)d_in[3];
    const float* Wv  = (const float*)d_in[4];
    const float* Wo  = (const float*)d_in[5];
    const float* bo  = (const float*)d_in[6];
    const float* g1  = (const float*)d_in[7];
    const float* b1l = (const float*)d_in[8];
    const float* W1  = (const float*)d_in[9];
    const float* b1  = (const float*)d_in[10];
    const float* W2  = (const float*)d_in[11];
    const float* b2  = (const float*)d_in[12];
    const float* g2  = (const float*)d_in[13];
    const float* b2l = (const float*)d_in[14];
    float* out = (float*)d_out;

    float* AO = (float*)d_ws;                                  // 4MB
    float* X  = AO + (size_t)BN * DIM;                         // 4MB
    unsigned long long* adjb = (unsigned long long*)(X + (size_t)BN * DIM); // 512KB
    unsigned int* Mex = (unsigned int*)(adjb + (size_t)N_ * N_ / 64);       // 8MB
    __bf16* Qb = (__bf16*)(Mex + (size_t)64 * 2048 * 2 * 8);   // 2MB
    __bf16* Kb = Qb + (size_t)BN * DIM;                        // 2MB
    __bf16* Vt = Kb + (size_t)BN * DIM;                        // [B][H][16][N] 2MB

    hipLaunchKernelGGL(k_adjbits, dim3(N_ * N_ / 256), dim3(256), 0, stream, adj, adjb);
    hipLaunchKernelGGL(k_adjexp, dim3(64 * 2048 * 2 / 256), dim3(256), 0, stream,
                       adjb, Mex);
    hipLaunchKernelGGL(k_qkv, dim3(BN / 32), dim3(512), 0, stream, h, Wq, Wk, Wv, Qb, Kb, Vt);
    hipLaunchKernelGGL(k_attn, dim3(B_ * NH * (N_ / 64)), dim3(512), 0, stream,
                       Qb, Kb, Vt, Mex, AO);
    hipLaunchKernelGGL(k_proj_ln, dim3(BN / 16), dim3(256), 0, stream,
                       AO, h, Wo, bo, g1, b1l, X);
    hipLaunchKernelGGL(k_ffn_ln, dim3(BN / 16), dim3(256), 0, stream,
                       X, W1, b1, W2, b2, g2, b2l, out);
}

// Round 6
// 123.820 us; speedup vs baseline: 1.9866x; 1.9866x over previous
//
#include <hip/hip_runtime.h>

#define B_   4
#define N_   2048
#define DIM  128
#define NH   8
#define HD   16
#define FFN_ 256
#define LN_EPS 1e-5f
#define BN   (B_*N_)
#define LOG2E 1.44269504f
#define RESCALE_THR 12.0f   // log2 units

#if __has_builtin(__builtin_amdgcn_exp2f)
#define EXP2(x) __builtin_amdgcn_exp2f(x)
#else
#define EXP2(x) exp2f(x)
#endif

typedef __bf16 bf16x8 __attribute__((ext_vector_type(8)));
typedef short  s16x8  __attribute__((ext_vector_type(8)));
typedef float  f32x16 __attribute__((ext_vector_type(16)));
typedef unsigned int u32x4 __attribute__((ext_vector_type(4)));

// ROCm clang declares __builtin_amdgcn_mfma_f32_32x32x16_bf16 with either
// <8 x bf16> or <8 x i16> operands depending on version. SFINAE both.
template<class T> struct as_short_vec { using type = s16x8; };

template <class T>
__device__ auto mfma_try(T a, T b, f32x16 c, int)
    -> decltype(__builtin_amdgcn_mfma_f32_32x32x16_bf16(a, b, c, 0, 0, 0)) {
  return __builtin_amdgcn_mfma_f32_32x32x16_bf16(a, b, c, 0, 0, 0);
}
template <class T>
__device__ f32x16 mfma_try(T a, T b, f32x16 c, long) {
  return __builtin_amdgcn_mfma_f32_32x32x16_bf16(
      __builtin_bit_cast(typename as_short_vec<T>::type, a),
      __builtin_bit_cast(typename as_short_vec<T>::type, b), c, 0, 0, 0);
}
__device__ __forceinline__ f32x16 mfma_bf(bf16x8 a, bf16x8 b, f32x16 c) {
  return mfma_try(a, b, c, 0);
}

// ---------------- adj (int32 0/1) -> 64-bit masks ----------------
__global__ __launch_bounds__(256) void k_adjbits(const int* __restrict__ adj,
                                                 unsigned long long* __restrict__ bits) {
    long long idx = (long long)blockIdx.x * 256 + threadIdx.x;
    int v = adj[idx] != 0;
    unsigned long long m = __ballot(v);
    if ((threadIdx.x & 63) == 0) bits[idx >> 6] = m;
}

// ------- expand adj bits into MFMA-fragment-ordered 16-bit AND masks -------
// Mex[((tg*2048+q)*2+hi)*8 + j] : u32 whose low/high 16 bits are 0xFFFF iff
// keys pos(2j),pos(2j+1) of tile tg are unmasked for query q,
// pos(r) = (r&3) + 8*(r>>2) + 4*hi.
__global__ __launch_bounds__(256) void k_adjexp(
    const unsigned long long* __restrict__ adjb, unsigned int* __restrict__ Mex) {
    const int g  = blockIdx.x * 256 + threadIdx.x;   // 64*2048*2 threads
    const int hi = g & 1;
    const int q  = (g >> 1) & 2047;
    const int tg = g >> 12;
    unsigned long long w = adjb[(size_t)q * 32 + (tg >> 1)];
    unsigned mm = (unsigned)(w >> ((tg & 1) * 32));
    const int pbase[8] = {0, 2, 8, 10, 16, 18, 24, 26};
    unsigned int out[8];
    #pragma unroll
    for (int j = 0; j < 8; ++j) {
        int base = pbase[j] + 4 * hi;
        unsigned lo = (mm >> base) & 1u;
        unsigned hb = (mm >> (base + 1)) & 1u;
        out[j] = (lo ? 0xFFFFu : 0u) | (hb ? 0xFFFF0000u : 0u);
    }
    unsigned int* dst = Mex + (size_t)g * 8;
    *(u32x4*)dst       = u32x4{out[0], out[1], out[2], out[3]};
    *(u32x4*)(dst + 4) = u32x4{out[4], out[5], out[6], out[7]};
}

// ---------------- fused QKV projection -> bf16, attention layouts ----------
// Qb,Kb: [B][H][N][HD] bf16 (Q pre-scaled by 0.25*log2e);
// Vt: [B][H][16][N] bf16 = V^T with keys permuted per 32-block.
__global__ __launch_bounds__(512) void k_qkv(const float* __restrict__ h,
    const float* __restrict__ Wq, const float* __restrict__ Wk, const float* __restrict__ Wv,
    __bf16* __restrict__ Qb, __bf16* __restrict__ Kb, __bf16* __restrict__ Vt) {
    __shared__ float hs[32][DIM];
    const int r0  = blockIdx.x * 32;
    const int tid = threadIdx.x;
    for (int i = tid; i < 32 * DIM; i += 512)
        hs[i >> 7][i & 127] = h[(size_t)r0 * DIM + i];
    __syncthreads();
    const int c     = tid & 127;
    const int rbase = (tid >> 7) * 8;
    float aq[8], ak[8], av[8];
    #pragma unroll
    for (int i = 0; i < 8; ++i) { aq[i] = 0.f; ak[i] = 0.f; av[i] = 0.f; }
    for (int k4 = 0; k4 < DIM; k4 += 4) {
        float4 hv[8];
        #pragma unroll
        for (int r = 0; r < 8; ++r) hv[r] = *(const float4*)&hs[rbase + r][k4];
        #pragma unroll
        for (int kk = 0; kk < 4; ++kk) {
            const int k = k4 + kk;
            float wq = Wq[k * DIM + c], wk = Wk[k * DIM + c], wv = Wv[k * DIM + c];
            #pragma unroll
            for (int r = 0; r < 8; ++r) {
                float hvv = ((const float*)&hv[r])[kk];
                aq[r] += hvv * wq; ak[r] += hvv * wk; av[r] += hvv * wv;
            }
        }
    }
    const int hh = c >> 4, d = c & 15;
    const int b  = r0 >> 11;
    const int n0 = (r0 & (N_ - 1)) + rbase;
    size_t qk = ((size_t)(b * NH + hh) * N_ + n0) * HD + d;
    size_t vh = ((size_t)(b * NH + hh) * HD + d) * N_;
    #pragma unroll
    for (int i = 0; i < 8; ++i) {
        Qb[qk + (size_t)i * HD] = (__bf16)(aq[i] * (0.25f * LOG2E));
        Kb[qk + (size_t)i * HD] = (__bf16)ak[i];
        int n  = n0 + i;
        int g  = (n >> 2) & 7;
        int ng = (g & 4) | ((g & 1) << 1) | ((g >> 1) & 1);
        Vt[vh + ((n & ~31) | (ng << 2) | (n & 3))] = (__bf16)av[i];
    }
}

// ---------------- masked flash attention, MFMA 32x32x16, 4-way split-K ----
// grid: B*H*(N/64) = 1024 blocks x 512 thr (8 waves).
// wave wv: wq = wv&1 (q sub-tile of 32 rows), kq = wv>>1 (K quarter, 512 keys).
// NOTE: min-waves arg stays at 4 (<=128 VGPR). Pinning 8 forced VGPR=32 and
// spilled the f32x16 accumulator: WRITE_SIZE 4MB -> 414MB, 3.3x slower (r5).
__global__ __launch_bounds__(512, 4) void k_attn(
    const __bf16* __restrict__ Qb, const __bf16* __restrict__ Kb,
    const __bf16* __restrict__ Vt, const unsigned int* __restrict__ Mex,
    float* __restrict__ AO) {
    const int bid  = blockIdx.x;
    const int qt   = bid & 31;          // N/64 = 32 q-tiles
    const int hh   = (bid >> 5) & 7;
    const int b    = bid >> 8;
    const int wv   = threadIdx.x >> 6;
    const int wq   = wv & 1;
    const int kq   = wv >> 1;
    const int lane = threadIdx.x & 63;
    const int l31  = lane & 31, hi = lane >> 5;
    const int q     = qt * 64 + wq * 32 + l31;
    const int kbase = kq * 512;
    const int NT    = 16;               // 16 tiles of 32 keys per quarter

    __shared__ float accL[3][2][64][9];
    __shared__ float mL[4][2][32], sL[4][2][32];

    const __bf16* Qh = Qb + (size_t)(b * NH + hh) * N_ * HD;
    const __bf16* Kh = Kb + (size_t)(b * NH + hh) * N_ * HD;
    const __bf16* Vh = Vt + ((size_t)(b * NH + hh) * HD + (l31 & 15)) * N_;
    const bool vload = (l31 < 16);
    const bf16x8 ones8 = __builtin_bit_cast(bf16x8,
        u32x4{0x3F803F80u, 0x3F803F80u, 0x3F803F80u, 0x3F803F80u});

    // Q^T B-frag: col q = l31, d = hi*8 + i — one 16B load.
    bf16x8 qf = *(const bf16x8*)(Qh + (size_t)q * HD + hi * 8);

    f32x16 acc;
    #pragma unroll
    for (int i = 0; i < 16; ++i) acc[i] = 0.f;
    float m = -1e30f;
    const f32x16 z = {};

    const unsigned int* Mp =
        Mex + ((size_t)(kq * NT) * 4096 + (size_t)q * 2 + hi) * 8;

    bf16x8 kf  = *(const bf16x8*)(Kh + (size_t)(kbase + l31) * HD + hi * 8);
    bf16x8 vfa = vload ? *(const bf16x8*)(Vh + kbase + hi * 8)      : ones8;
    bf16x8 vfb = vload ? *(const bf16x8*)(Vh + kbase + 16 + hi * 8) : ones8;
    u32x4  ma  = *(const u32x4*)Mp;
    u32x4  mb  = *(const u32x4*)(Mp + 4);

    for (int t = 0; t < NT; ++t) {
        // prefetch tile t+1
        bf16x8 kf_n = kf, vfa_n = vfa, vfb_n = vfb;
        u32x4 ma_n = ma, mb_n = mb;
        if (t + 1 < NT) {
            const int k1 = kbase + (t + 1) * 32;
            kf_n = *(const bf16x8*)(Kh + (size_t)(k1 + l31) * HD + hi * 8);
            if (vload) {
                vfa_n = *(const bf16x8*)(Vh + k1 + hi * 8);
                vfb_n = *(const bf16x8*)(Vh + k1 + 16 + hi * 8);
            }
            const unsigned int* Mq = Mp + 32768;
            ma_n = *(const u32x4*)Mq;
            mb_n = *(const u32x4*)(Mq + 4);
        }

        // S^T[k][q] (log2-scaled): D: q = l31, k = (r&3)+8*(r>>2)+4*hi
        f32x16 st = mfma_bf(kf, qf, z);

        // local (lane-half) tile max over raw scores
        float a0 = fmaxf(fmaxf(st[0], st[1]), st[2]);
        float a1 = fmaxf(fmaxf(st[3], st[4]), st[5]);
        float a2 = fmaxf(fmaxf(st[6], st[7]), st[8]);
        float a3 = fmaxf(fmaxf(st[9], st[10]), st[11]);
        float a4 = fmaxf(fmaxf(st[12], st[13]), st[14]);
        float b0 = fmaxf(fmaxf(a0, a1), a2);
        float b1 = fmaxf(fmaxf(a3, a4), st[15]);
        float tm = fmaxf(b0, b1);

        // deferred rescale; cross-half agreement only inside the rare branch.
        // Invariant after: st - m <= THR for every lane (by __any over 64 lanes).
        if (__any(tm > m + RESCALE_THR)) {
            float tmj = fmaxf(tm, __shfl_xor(tm, 32));
            float mn  = fmaxf(m, tmj);
            float sc  = EXP2(m - mn);
            #pragma unroll
            for (int r = 0; r < 9; ++r) acc[r] *= sc;
            m = mn;
        }

        // p = 2^(st - m) <= 2^12; mask applied on packed bf16 via AND
        float p[16];
        #pragma unroll
        for (int r = 0; r < 16; ++r) p[r] = EXP2(st[r] - m);
        bf16x8 pa, pb;
        #pragma unroll
        for (int r = 0; r < 8; ++r) { pa[r] = (__bf16)p[r]; pb[r] = (__bf16)p[r + 8]; }
        pa = __builtin_bit_cast(bf16x8, __builtin_bit_cast(u32x4, pa) & ma);
        pb = __builtin_bit_cast(bf16x8, __builtin_bit_cast(u32x4, pb) & mb);

        // PV; A rows 16..31 are register-ones -> acc[8] accumulates sum(p)
        acc = mfma_bf(vfa, pa, acc);
        acc = mfma_bf(vfb, pb, acc);

        kf = kf_n; vfa = vfa_n; vfb = vfb_n; ma = ma_n; mb = mb_n;
        Mp += 32768;
    }

    const float sum = acc[8];

    // ---- 4-way split-K merge through LDS ----
    if (kq != 0) {
        #pragma unroll
        for (int r = 0; r < 8; ++r) accL[kq - 1][wq][lane][r] = acc[r];
    }
    if (hi == 0) { mL[kq][wq][l31] = m; sL[kq][wq][l31] = sum; }
    __syncthreads();
    if (kq == 0) {
        float M = m;
        #pragma unroll
        for (int i = 1; i < 4; ++i) M = fmaxf(M, mL[i][wq][l31]);
        float e0 = EXP2(m - M);
        float s  = sum * e0;
        float e[3];
        #pragma unroll
        for (int i = 0; i < 3; ++i) {
            e[i] = EXP2(mL[i + 1][wq][l31] - M);
            s += sL[i + 1][wq][l31] * e[i];
        }
        float inv = 1.f / s;
        float o[8];
        #pragma unroll
        for (int r = 0; r < 8; ++r) {
            float v = acc[r] * e0;
            #pragma unroll
            for (int i = 0; i < 3; ++i) v += accL[i][wq][lane][r] * e[i];
            o[r] = v * inv;
        }
        float* op = AO + ((size_t)(b * N_ + q)) * DIM + hh * HD + 4 * hi;
        float4 o0 = { o[0], o[1], o[2], o[3] };
        float4 o1 = { o[4], o[5], o[6], o[7] };
        *(float4*)op       = o0;   // d = 4*hi + 0..3
        *(float4*)(op + 8) = o1;   // d = 8 + 4*hi + 0..3
    }
}

// ---------------- Wo projection + residual + LN1 ----------------
// 16 rows/block, 256 threads, grid BN/16.
__global__ __launch_bounds__(256) void k_proj_ln(
    const float* __restrict__ AO, const float* __restrict__ h,
    const float* __restrict__ Wo, const float* __restrict__ bo,
    const float* __restrict__ g, const float* __restrict__ bln,
    float* __restrict__ X) {
    const int r0  = blockIdx.x * 16;
    const int tid = threadIdx.x;
    __shared__ float a[16][DIM];
    __shared__ float vv[16][DIM];
    __shared__ float mu_s[16], rs_s[16];
    for (int i = tid; i < 16 * DIM; i += 256)
        a[i >> 7][i & 127] = AO[(size_t)r0 * DIM + i];
    __syncthreads();
    const int c = tid & 127, rg = tid >> 7;
    float accv[8];
    float bov = bo[c];
    #pragma unroll
    for (int r = 0; r < 8; ++r) accv[r] = bov;
    for (int k = 0; k < DIM; ++k) {
        float w = Wo[k * DIM + c];
        #pragma unroll
        for (int r = 0; r < 8; ++r) accv[r] += a[rg * 8 + r][k] * w;
    }
    #pragma unroll
    for (int r = 0; r < 8; ++r)
        vv[rg * 8 + r][c] = accv[r] + h[((size_t)(r0 + rg * 8 + r)) * DIM + c];
    __syncthreads();
    const int wvx = tid >> 6, ln = tid & 63;
    #pragma unroll
    for (int i = 0; i < 4; ++i) {
        int r = wvx * 4 + i;
        float x0 = vv[r][ln], x1 = vv[r][ln + 64];
        float s = x0 + x1, s2 = x0 * x0 + x1 * x1;
        for (int off = 1; off < 64; off <<= 1) {
            s  += __shfl_xor(s,  off);
            s2 += __shfl_xor(s2, off);
        }
        if (ln == 0) {
            float mu = s * (1.f / DIM);
            float var = s2 * (1.f / DIM) - mu * mu;
            mu_s[r] = mu; rs_s[r] = rsqrtf(var + LN_EPS);
        }
    }
    __syncthreads();
    float gc = g[c], bc = bln[c];
    #pragma unroll
    for (int r = 0; r < 8; ++r) {
        int rr = rg * 8 + r;
        X[((size_t)(r0 + rr)) * DIM + c] = (vv[rr][c] - mu_s[rr]) * rs_s[rr] * gc + bc;
    }
}

// ---------------- FFN + residual + LN2 ----------------
// 16 rows/block, 256 threads, grid BN/16.
__global__ __launch_bounds__(256) void k_ffn_ln(
    const float* __restrict__ X,
    const float* __restrict__ W1, const float* __restrict__ b1,
    const float* __restrict__ W2, const float* __restrict__ b2,
    const float* __restrict__ g, const float* __restrict__ bln,
    float* __restrict__ out) {
    const int r0  = blockIdx.x * 16;
    const int tid = threadIdx.x;
    __shared__ float xs[16][DIM];
    __shared__ float ts[16][FFN_];
    __shared__ float vv[16][DIM];
    __shared__ float mu_s[16], rs_s[16];
    for (int i = tid; i < 16 * DIM; i += 256)
        xs[i >> 7][i & 127] = X[(size_t)r0 * DIM + i];
    __syncthreads();
    {
        float accv[16];
        float bb = b1[tid];
        #pragma unroll
        for (int r = 0; r < 16; ++r) accv[r] = bb;
        for (int k = 0; k < DIM; ++k) {
            float w = W1[k * FFN_ + tid];
            #pragma unroll
            for (int r = 0; r < 16; ++r) accv[r] += xs[r][k] * w;
        }
        #pragma unroll
        for (int r = 0; r < 16; ++r) ts[r][tid] = fmaxf(accv[r], 0.f);
    }
    __syncthreads();
    {
        const int c = tid & 127, rg = tid >> 7;
        float y[8];
        float bb = b2[c];
        #pragma unroll
        for (int i = 0; i < 8; ++i) y[i] = bb;
        for (int k = 0; k < FFN_; ++k) {
            float w = W2[k * DIM + c];
            #pragma unroll
            for (int i = 0; i < 8; ++i) y[i] += ts[rg * 8 + i][k] * w;
        }
        #pragma unroll
        for (int i = 0; i < 8; ++i)
            vv[rg * 8 + i][c] = y[i] + xs[rg * 8 + i][c];
    }
    __syncthreads();
    {
        const int wvx = tid >> 6, ln = tid & 63;
        #pragma unroll
        for (int i = 0; i < 4; ++i) {
            int rr = wvx * 4 + i;
            float x0 = vv[rr][ln], x1 = vv[rr][ln + 64];
            float s = x0 + x1, s2 = x0 * x0 + x1 * x1;
            for (int off = 1; off < 64; off <<= 1) {
                s  += __shfl_xor(s,  off);
                s2 += __shfl_xor(s2, off);
            }
            if (ln == 0) {
                float mu = s * (1.f / DIM);
                float var = s2 * (1.f / DIM) - mu * mu;
                mu_s[rr] = mu; rs_s[rr] = rsqrtf(var + LN_EPS);
            }
        }
    }
    __syncthreads();
    {
        const int c = tid & 127, rg = tid >> 7;
        float gc = g[c], bc = bln[c];
        #pragma unroll
        for (int i = 0; i < 8; ++i) {
            int rr = rg * 8 + i;
            out[((size_t)(r0 + rr)) * DIM + c] =
                (vv[rr][c] - mu_s[rr]) * rs_s[rr] * gc + bc;
        }
    }
}

extern "C" void kernel_launch(void* const* d_in, const int* in_sizes, int n_in,
                              void* d_out, int out_size, void* d_ws, size_t ws_size,
                              hipStream_t stream) {
    const int*   adj = (const int*)  d_in[0];
    const float* h   = (const float*)d_in[1];
    const float* Wq  = (const float*)d_in[2];
    const float* Wk  = (const float*)d_in[3];
    const float* Wv  = (const float*)d_in[4];
    const float* Wo  = (const float*)d_in[5];
    const float* bo  = (const float*)d_in[6];
    const float* g1  = (const float*)d_in[7];
    const float* b1l = (const float*)d_in[8];
    const float* W1  = (const float*)d_in[9];
    const float* b1  = (const float*)d_in[10];
    const float* W2  = (const float*)d_in[11];
    const float* b2  = (const float*)d_in[12];
    const float* g2  = (const float*)d_in[13];
    const float* b2l = (const float*)d_in[14];
    float* out = (float*)d_out;

    float* AO = (float*)d_ws;                                  // 4MB
    float* X  = AO + (size_t)BN * DIM;                         // 4MB
    unsigned long long* adjb = (unsigned long long*)(X + (size_t)BN * DIM); // 512KB
    unsigned int* Mex = (unsigned int*)(adjb + (size_t)N_ * N_ / 64);       // 8MB
    __bf16* Qb = (__bf16*)(Mex + (size_t)64 * 2048 * 2 * 8);   // 2MB
    __bf16* Kb = Qb + (size_t)BN * DIM;                        // 2MB
    __bf16* Vt = Kb + (size_t)BN * DIM;                        // [B][H][16][N] 2MB

    hipLaunchKernelGGL(k_adjbits, dim3(N_ * N_ / 256), dim3(256), 0, stream, adj, adjb);
    hipLaunchKernelGGL(k_adjexp, dim3(64 * 2048 * 2 / 256), dim3(256), 0, stream,
                       adjb, Mex);
    hipLaunchKernelGGL(k_qkv, dim3(BN / 32), dim3(512), 0, stream, h, Wq, Wk, Wv, Qb, Kb, Vt);
    hipLaunchKernelGGL(k_attn, dim3(B_ * NH * (N_ / 64)), dim3(512), 0, stream,
                       Qb, Kb, Vt, Mex, AO);
    hipLaunchKernelGGL(k_proj_ln, dim3(BN / 16), dim3(256), 0, stream,
                       AO, h, Wo, bo, g1, b1l, X);
    hipLaunchKernelGGL(k_ffn_ln, dim3(BN / 16), dim3(256), 0, stream,
                       X, W1, b1, W2, b2, g2, b2l, out);
}

// Round 7
// 102.436 us; speedup vs baseline: 2.4013x; 1.2088x over previous
//
#include <hip/hip_runtime.h>

#define B_   4
#define N_   2048
#define DIM  128
#define NH   8
#define HD   16
#define FFN_ 256
#define LN_EPS 1e-5f
#define BN   (B_*N_)
#define LOG2E 1.44269504f
#define RESCALE_THR 12.0f   // log2 units

#if __has_builtin(__builtin_amdgcn_exp2f)
#define EXP2(x) __builtin_amdgcn_exp2f(x)
#else
#define EXP2(x) exp2f(x)
#endif

typedef __bf16 bf16x8 __attribute__((ext_vector_type(8)));
typedef short  s16x8  __attribute__((ext_vector_type(8)));
typedef float  f32x16 __attribute__((ext_vector_type(16)));
typedef unsigned int u32x4 __attribute__((ext_vector_type(4)));

template<class T> struct as_short_vec { using type = s16x8; };

template <class T>
__device__ auto mfma_try(T a, T b, f32x16 c, int)
    -> decltype(__builtin_amdgcn_mfma_f32_32x32x16_bf16(a, b, c, 0, 0, 0)) {
  return __builtin_amdgcn_mfma_f32_32x32x16_bf16(a, b, c, 0, 0, 0);
}
template <class T>
__device__ f32x16 mfma_try(T a, T b, f32x16 c, long) {
  return __builtin_amdgcn_mfma_f32_32x32x16_bf16(
      __builtin_bit_cast(typename as_short_vec<T>::type, a),
      __builtin_bit_cast(typename as_short_vec<T>::type, b), c, 0, 0, 0);
}
__device__ __forceinline__ f32x16 mfma_bf(bf16x8 a, bf16x8 b, f32x16 c) {
  return mfma_try(a, b, c, 0);
}

// ---------------- adj (int32 0/1) -> 64-bit masks ----------------
__global__ __launch_bounds__(256) void k_adjbits(const int* __restrict__ adj,
                                                 unsigned long long* __restrict__ bits) {
    long long idx = (long long)blockIdx.x * 256 + threadIdx.x;
    int v = adj[idx] != 0;
    unsigned long long m = __ballot(v);
    if ((threadIdx.x & 63) == 0) bits[idx >> 6] = m;
}

// ------- expand adj bits into MFMA-fragment-ordered 16-bit AND masks -------
__global__ __launch_bounds__(256) void k_adjexp(
    const unsigned long long* __restrict__ adjb, unsigned int* __restrict__ Mex) {
    const int g  = blockIdx.x * 256 + threadIdx.x;   // 64*2048*2 threads
    const int hi = g & 1;
    const int q  = (g >> 1) & 2047;
    const int tg = g >> 12;
    unsigned long long w = adjb[(size_t)q * 32 + (tg >> 1)];
    unsigned mm = (unsigned)(w >> ((tg & 1) * 32));
    const int pbase[8] = {0, 2, 8, 10, 16, 18, 24, 26};
    unsigned int out[8];
    #pragma unroll
    for (int j = 0; j < 8; ++j) {
        int base = pbase[j] + 4 * hi;
        unsigned lo = (mm >> base) & 1u;
        unsigned hb = (mm >> (base + 1)) & 1u;
        out[j] = (lo ? 0xFFFFu : 0u) | (hb ? 0xFFFF0000u : 0u);
    }
    unsigned int* dst = Mex + (size_t)g * 8;
    *(u32x4*)dst       = u32x4{out[0], out[1], out[2], out[3]};
    *(u32x4*)(dst + 4) = u32x4{out[4], out[5], out[6], out[7]};
}

// ------- cast+transpose FFN weights to bf16, n-major -------
// W1 [128][256] f32 -> W1t [256][128] bf16 ; W2 [256][128] f32 -> W2t [128][256] bf16
__global__ __launch_bounds__(256) void k_wcast(const float* __restrict__ W1,
                                               const float* __restrict__ W2,
                                               __bf16* __restrict__ W1t,
                                               __bf16* __restrict__ W2t) {
    const int g = blockIdx.x * 256 + threadIdx.x;    // 32768 threads
    {
        int k = g >> 8, n = g & 255;
        W1t[(size_t)n * 128 + k] = (__bf16)W1[(size_t)k * 256 + n];
    }
    {
        int k = g >> 7, n = g & 127;
        W2t[(size_t)n * 256 + k] = (__bf16)W2[(size_t)k * 128 + n];
    }
}

// ---------------- fused QKV projection -> bf16, attention layouts ----------
__global__ __launch_bounds__(512) void k_qkv(const float* __restrict__ h,
    const float* __restrict__ Wq, const float* __restrict__ Wk, const float* __restrict__ Wv,
    __bf16* __restrict__ Qb, __bf16* __restrict__ Kb, __bf16* __restrict__ Vt) {
    __shared__ float hs[32][DIM];
    const int r0  = blockIdx.x * 32;
    const int tid = threadIdx.x;
    for (int i = tid; i < 32 * DIM; i += 512)
        hs[i >> 7][i & 127] = h[(size_t)r0 * DIM + i];
    __syncthreads();
    const int c     = tid & 127;
    const int rbase = (tid >> 7) * 8;
    float aq[8], ak[8], av[8];
    #pragma unroll
    for (int i = 0; i < 8; ++i) { aq[i] = 0.f; ak[i] = 0.f; av[i] = 0.f; }
    for (int k4 = 0; k4 < DIM; k4 += 4) {
        float4 hv[8];
        #pragma unroll
        for (int r = 0; r < 8; ++r) hv[r] = *(const float4*)&hs[rbase + r][k4];
        #pragma unroll
        for (int kk = 0; kk < 4; ++kk) {
            const int k = k4 + kk;
            float wq = Wq[k * DIM + c], wk = Wk[k * DIM + c], wv = Wv[k * DIM + c];
            #pragma unroll
            for (int r = 0; r < 8; ++r) {
                float hvv = ((const float*)&hv[r])[kk];
                aq[r] += hvv * wq; ak[r] += hvv * wk; av[r] += hvv * wv;
            }
        }
    }
    const int hh = c >> 4, d = c & 15;
    const int b  = r0 >> 11;
    const int n0 = (r0 & (N_ - 1)) + rbase;
    size_t qk = ((size_t)(b * NH + hh) * N_ + n0) * HD + d;
    size_t vh = ((size_t)(b * NH + hh) * HD + d) * N_;
    #pragma unroll
    for (int i = 0; i < 8; ++i) {
        Qb[qk + (size_t)i * HD] = (__bf16)(aq[i] * (0.25f * LOG2E));
        Kb[qk + (size_t)i * HD] = (__bf16)ak[i];
        int n  = n0 + i;
        int g  = (n >> 2) & 7;
        int ng = (g & 4) | ((g & 1) << 1) | ((g >> 1) & 1);
        Vt[vh + ((n & ~31) | (ng << 2) | (n & 3))] = (__bf16)av[i];
    }
}

// ---------------- masked flash attention, MFMA 32x32x16, 8-way split-K ----
// grid: B*H*(N/32) = 2048 blocks x 512 thr (8 waves).
// wave kq processes keys [kq*256, kq*256+256) for the block's 32 q-rows.
// VGPR must stay <=64 for 8 waves/SIMD — do NOT pin launch_bounds min-waves
// above 4 (r5: pinning 8 forced VGPR=32 and spilled acc: 3.3x slower).
__global__ __launch_bounds__(512, 4) void k_attn(
    const __bf16* __restrict__ Qb, const __bf16* __restrict__ Kb,
    const __bf16* __restrict__ Vt, const unsigned int* __restrict__ Mex,
    float* __restrict__ AO) {
    const int bid  = blockIdx.x;
    const int qt   = bid & 63;          // N/32 = 64 q-tiles
    const int hh   = (bid >> 6) & 7;
    const int b    = bid >> 9;
    const int kq   = threadIdx.x >> 6;  // wave = K eighth
    const int lane = threadIdx.x & 63;
    const int l31  = lane & 31, hi = lane >> 5;
    const int q     = qt * 32 + l31;
    const int kbase = kq * 256;
    const int NT    = 8;                // 8 tiles of 32 keys per eighth

    __shared__ float accL[7][64][9];
    __shared__ float mL[8][32], sL[8][32];

    const __bf16* Qh = Qb + (size_t)(b * NH + hh) * N_ * HD;
    const __bf16* Kh = Kb + (size_t)(b * NH + hh) * N_ * HD;
    const __bf16* Vh = Vt + ((size_t)(b * NH + hh) * HD + (l31 & 15)) * N_;
    const bool vload = (l31 < 16);
    const bf16x8 ones8 = __builtin_bit_cast(bf16x8,
        u32x4{0x3F803F80u, 0x3F803F80u, 0x3F803F80u, 0x3F803F80u});

    bf16x8 qf = *(const bf16x8*)(Qh + (size_t)q * HD + hi * 8);

    f32x16 acc;
    #pragma unroll
    for (int i = 0; i < 16; ++i) acc[i] = 0.f;
    float m = -1e30f;
    const f32x16 z = {};

    const unsigned int* Mp =
        Mex + ((size_t)(kq * NT) * 4096 + (size_t)q * 2 + hi) * 8;

    bf16x8 kf  = *(const bf16x8*)(Kh + (size_t)(kbase + l31) * HD + hi * 8);
    bf16x8 vfa = vload ? *(const bf16x8*)(Vh + kbase + hi * 8)      : ones8;
    bf16x8 vfb = vload ? *(const bf16x8*)(Vh + kbase + 16 + hi * 8) : ones8;
    u32x4  ma  = *(const u32x4*)Mp;
    u32x4  mb  = *(const u32x4*)(Mp + 4);

    for (int t = 0; t < NT; ++t) {
        bf16x8 kf_n = kf, vfa_n = vfa, vfb_n = vfb;
        u32x4 ma_n = ma, mb_n = mb;
        if (t + 1 < NT) {
            const int k1 = kbase + (t + 1) * 32;
            kf_n = *(const bf16x8*)(Kh + (size_t)(k1 + l31) * HD + hi * 8);
            if (vload) {
                vfa_n = *(const bf16x8*)(Vh + k1 + hi * 8);
                vfb_n = *(const bf16x8*)(Vh + k1 + 16 + hi * 8);
            }
            const unsigned int* Mq = Mp + 32768;
            ma_n = *(const u32x4*)Mq;
            mb_n = *(const u32x4*)(Mq + 4);
        }

        // S^T[k][q] (log2-scaled): D: q = l31, k = (r&3)+8*(r>>2)+4*hi
        f32x16 st = mfma_bf(kf, qf, z);

        float a0 = fmaxf(fmaxf(st[0], st[1]), st[2]);
        float a1 = fmaxf(fmaxf(st[3], st[4]), st[5]);
        float a2 = fmaxf(fmaxf(st[6], st[7]), st[8]);
        float a3 = fmaxf(fmaxf(st[9], st[10]), st[11]);
        float a4 = fmaxf(fmaxf(st[12], st[13]), st[14]);
        float b0 = fmaxf(fmaxf(a0, a1), a2);
        float b1 = fmaxf(fmaxf(a3, a4), st[15]);
        float tm = fmaxf(b0, b1);

        if (__any(tm > m + RESCALE_THR)) {
            float tmj = fmaxf(tm, __shfl_xor(tm, 32));
            float mn  = fmaxf(m, tmj);
            float sc  = EXP2(m - mn);
            #pragma unroll
            for (int r = 0; r < 9; ++r) acc[r] *= sc;
            m = mn;
        }

        float p[16];
        #pragma unroll
        for (int r = 0; r < 16; ++r) p[r] = EXP2(st[r] - m);
        bf16x8 pa, pb;
        #pragma unroll
        for (int r = 0; r < 8; ++r) { pa[r] = (__bf16)p[r]; pb[r] = (__bf16)p[r + 8]; }
        pa = __builtin_bit_cast(bf16x8, __builtin_bit_cast(u32x4, pa) & ma);
        pb = __builtin_bit_cast(bf16x8, __builtin_bit_cast(u32x4, pb) & mb);

        // PV; A rows 16..31 are register-ones -> acc[8] accumulates sum(p)
        acc = mfma_bf(vfa, pa, acc);
        acc = mfma_bf(vfb, pb, acc);

        kf = kf_n; vfa = vfa_n; vfb = vfb_n; ma = ma_n; mb = mb_n;
        Mp += 32768;
    }

    const float sum = acc[8];

    // ---- 8-way split-K merge through LDS ----
    if (kq != 0) {
        #pragma unroll
        for (int r = 0; r < 8; ++r) accL[kq - 1][lane][r] = acc[r];
    }
    if (hi == 0) { mL[kq][l31] = m; sL[kq][l31] = sum; }
    __syncthreads();
    if (kq == 0) {
        float M = m;
        #pragma unroll
        for (int i = 1; i < 8; ++i) M = fmaxf(M, mL[i][l31]);
        float e0 = EXP2(m - M);
        float s  = sum * e0;
        float e[7];
        #pragma unroll
        for (int i = 0; i < 7; ++i) {
            e[i] = EXP2(mL[i + 1][l31] - M);
            s += sL[i + 1][l31] * e[i];
        }
        float inv = 1.f / s;
        float o[8];
        #pragma unroll
        for (int r = 0; r < 8; ++r) {
            float v = acc[r] * e0;
            #pragma unroll
            for (int i = 0; i < 7; ++i) v += accL[i][lane][r] * e[i];
            o[r] = v * inv;
        }
        float* op = AO + ((size_t)(b * N_ + q)) * DIM + hh * HD + 4 * hi;
        float4 o0 = { o[0], o[1], o[2], o[3] };
        float4 o1 = { o[4], o[5], o[6], o[7] };
        *(float4*)op       = o0;
        *(float4*)(op + 8) = o1;
    }
}

// ---------------- Wo projection + residual + LN1 (also emits bf16 X) ------
__global__ __launch_bounds__(256) void k_proj_ln(
    const float* __restrict__ AO, const float* __restrict__ h,
    const float* __restrict__ Wo, const float* __restrict__ bo,
    const float* __restrict__ g, const float* __restrict__ bln,
    float* __restrict__ X, __bf16* __restrict__ Xb) {
    const int r0  = blockIdx.x * 16;
    const int tid = threadIdx.x;
    __shared__ float a[16][DIM];
    __shared__ float vv[16][DIM];
    __shared__ float mu_s[16], rs_s[16];
    for (int i = tid; i < 16 * DIM; i += 256)
        a[i >> 7][i & 127] = AO[(size_t)r0 * DIM + i];
    __syncthreads();
    const int c = tid & 127, rg = tid >> 7;
    float accv[8];
    float bov = bo[c];
    #pragma unroll
    for (int r = 0; r < 8; ++r) accv[r] = bov;
    for (int k = 0; k < DIM; ++k) {
        float w = Wo[k * DIM + c];
        #pragma unroll
        for (int r = 0; r < 8; ++r) accv[r] += a[rg * 8 + r][k] * w;
    }
    #pragma unroll
    for (int r = 0; r < 8; ++r)
        vv[rg * 8 + r][c] = accv[r] + h[((size_t)(r0 + rg * 8 + r)) * DIM + c];
    __syncthreads();
    const int wvx = tid >> 6, ln = tid & 63;
    #pragma unroll
    for (int i = 0; i < 4; ++i) {
        int r = wvx * 4 + i;
        float x0 = vv[r][ln], x1 = vv[r][ln + 64];
        float s = x0 + x1, s2 = x0 * x0 + x1 * x1;
        for (int off = 1; off < 64; off <<= 1) {
            s  += __shfl_xor(s,  off);
            s2 += __shfl_xor(s2, off);
        }
        if (ln == 0) {
            float mu = s * (1.f / DIM);
            float var = s2 * (1.f / DIM) - mu * mu;
            mu_s[r] = mu; rs_s[r] = rsqrtf(var + LN_EPS);
        }
    }
    __syncthreads();
    float gc = g[c], bc = bln[c];
    #pragma unroll
    for (int r = 0; r < 8; ++r) {
        int rr = rg * 8 + r;
        float val = (vv[rr][c] - mu_s[rr]) * rs_s[rr] * gc + bc;
        size_t o = ((size_t)(r0 + rr)) * DIM + c;
        X[o]  = val;
        Xb[o] = (__bf16)val;
    }
}

// ---------------- FFN + residual + LN2, MFMA ----------------
// grid: BN/32 = 256 blocks x 256 thr (4 waves). 32 rows/block.
// GEMM1: wave w -> col-tiles w, w+4 of T[32][256]; GEMM2: col-tile w of C2.
__global__ __launch_bounds__(256) void k_ffn_ln(
    const float* __restrict__ X, const __bf16* __restrict__ Xb,
    const __bf16* __restrict__ W1t, const float* __restrict__ b1,
    const __bf16* __restrict__ W2t, const float* __restrict__ b2,
    const float* __restrict__ g, const float* __restrict__ bln,
    float* __restrict__ out) {
    const int r0   = blockIdx.x * 32;
    const int tid  = threadIdx.x;
    const int w    = tid >> 6;
    const int lane = tid & 63;
    const int l31  = lane & 31, hi = lane >> 5;

    __shared__ __bf16 Xs[32 * 128];   // XOR-swizzled: byte ^= (row&7)<<4
    __shared__ __bf16 Ts[32 * 256];   // XOR-swizzled: byte ^= (row&7)<<4
    __shared__ float  vv[32][DIM];

    // stage Xb (32x128 bf16) into swizzled LDS: 512 bf16x8 units
    for (int i = tid; i < 512; i += 256) {
        int row = i >> 4, u = i & 15;
        bf16x8 v = *(const bf16x8*)(Xb + (size_t)(r0 + row) * DIM + u * 8);
        int byte = (row * 256 + u * 16) ^ ((row & 7) << 4);
        *(bf16x8*)((char*)Xs + byte) = v;
    }
    __syncthreads();

    // ---- GEMM1: T = relu(X @ W1 + b1), two 32-col tiles per wave ----
    f32x16 acc1a, acc1b;
    #pragma unroll
    for (int i = 0; i < 16; ++i) { acc1a[i] = 0.f; acc1b[i] = 0.f; }
    #pragma unroll
    for (int kk = 0; kk < 8; ++kk) {
        int byte = (l31 * 256 + kk * 32 + hi * 16) ^ ((l31 & 7) << 4);
        bf16x8 a = *(const bf16x8*)((const char*)Xs + byte);
        bf16x8 bA = *(const bf16x8*)(W1t + (size_t)(w * 32 + l31) * 128 + kk * 16 + hi * 8);
        bf16x8 bB = *(const bf16x8*)(W1t + (size_t)((w + 4) * 32 + l31) * 128 + kk * 16 + hi * 8);
        acc1a = mfma_bf(a, bA, acc1a);
        acc1b = mfma_bf(a, bB, acc1b);
    }
    #pragma unroll
    for (int ct = 0; ct < 2; ++ct) {
        const f32x16& ac = ct ? acc1b : acc1a;
        int n = (w + ct * 4) * 32 + l31;
        float bb = b1[n];
        #pragma unroll
        for (int r = 0; r < 16; ++r) {
            int mm = (r & 3) + 8 * (r >> 2) + 4 * hi;
            float v = fmaxf(ac[r] + bb, 0.f);
            int byte = (mm * 512 + n * 2) ^ ((mm & 7) << 4);
            *(__bf16*)((char*)Ts + byte) = (__bf16)v;
        }
    }
    __syncthreads();

    // ---- GEMM2: C2 = T @ W2, one 32-col tile per wave ----
    f32x16 acc2;
    #pragma unroll
    for (int i = 0; i < 16; ++i) acc2[i] = 0.f;
    #pragma unroll
    for (int kk = 0; kk < 16; ++kk) {
        int byte = (l31 * 512 + kk * 32 + hi * 16) ^ ((l31 & 7) << 4);
        bf16x8 a = *(const bf16x8*)((const char*)Ts + byte);
        bf16x8 bb = *(const bf16x8*)(W2t + (size_t)(w * 32 + l31) * 256 + kk * 16 + hi * 8);
        acc2 = mfma_bf(a, bb, acc2);
    }
    {
        int n = w * 32 + l31;
        float bb = b2[n];
        #pragma unroll
        for (int r = 0; r < 16; ++r) {
            int mm = (r & 3) + 8 * (r >> 2) + 4 * hi;
            vv[mm][n] = acc2[r] + bb + X[(size_t)(r0 + mm) * DIM + n];
        }
    }
    __syncthreads();

    // ---- LN2: wave w handles rows w*8..w*8+7; butterfly leaves sums in all lanes
    const int ln = lane;
    float gc0 = g[ln], bc0 = bln[ln], gc1 = g[ln + 64], bc1 = bln[ln + 64];
    #pragma unroll
    for (int i = 0; i < 8; ++i) {
        int rr = w * 8 + i;
        float x0 = vv[rr][ln], x1 = vv[rr][ln + 64];
        float s = x0 + x1, s2 = x0 * x0 + x1 * x1;
        for (int off = 1; off < 64; off <<= 1) {
            s  += __shfl_xor(s,  off);
            s2 += __shfl_xor(s2, off);
        }
        float mu  = s * (1.f / DIM);
        float var = s2 * (1.f / DIM) - mu * mu;
        float rs  = rsqrtf(var + LN_EPS);
        size_t o = (size_t)(r0 + rr) * DIM;
        out[o + ln]      = (x0 - mu) * rs * gc0 + bc0;
        out[o + ln + 64] = (x1 - mu) * rs * gc1 + bc1;
    }
}

extern "C" void kernel_launch(void* const* d_in, const int* in_sizes, int n_in,
                              void* d_out, int out_size, void* d_ws, size_t ws_size,
                              hipStream_t stream) {
    const int*   adj = (const int*)  d_in[0];
    const float* h   = (const float*)d_in[1];
    const float* Wq  = (const float*)d_in[2];
    const float* Wk  = (const float*)d_in[3];
    const float* Wv  = (const float*)d_in[4];
    const float* Wo  = (const float*)d_in[5];
    const float* bo  = (const float*)d_in[6];
    const float* g1  = (const float*)d_in[7];
    const float* b1l = (const float*)d_in[8];
    const float* W1  = (const float*)d_in[9];
    const float* b1  = (const float*)d_in[10];
    const float* W2  = (const float*)d_in[11];
    const float* b2  = (const float*)d_in[12];
    const float* g2  = (const float*)d_in[13];
    const float* b2l = (const float*)d_in[14];
    float* out = (float*)d_out;

    float* AO = (float*)d_ws;                                  // 4MB
    float* X  = AO + (size_t)BN * DIM;                         // 4MB
    unsigned long long* adjb = (unsigned long long*)(X + (size_t)BN * DIM); // 512KB
    unsigned int* Mex = (unsigned int*)(adjb + (size_t)N_ * N_ / 64);       // 8MB
    __bf16* Qb  = (__bf16*)(Mex + (size_t)64 * 2048 * 2 * 8);  // 2MB
    __bf16* Kb  = Qb + (size_t)BN * DIM;                       // 2MB
    __bf16* Vt  = Kb + (size_t)BN * DIM;                       // 2MB
    __bf16* Xb  = Vt + (size_t)BN * DIM;                       // 2MB
    __bf16* W1t = Xb + (size_t)BN * DIM;                       // 64KB
    __bf16* W2t = W1t + (size_t)DIM * FFN_;                    // 64KB

    hipLaunchKernelGGL(k_adjbits, dim3(N_ * N_ / 256), dim3(256), 0, stream, adj, adjb);
    hipLaunchKernelGGL(k_adjexp, dim3(64 * 2048 * 2 / 256), dim3(256), 0, stream,
                       adjb, Mex);
    hipLaunchKernelGGL(k_wcast, dim3(128), dim3(256), 0, stream, W1, W2, W1t, W2t);
    hipLaunchKernelGGL(k_qkv, dim3(BN / 32), dim3(512), 0, stream, h, Wq, Wk, Wv, Qb, Kb, Vt);
    hipLaunchKernelGGL(k_attn, dim3(B_ * NH * (N_ / 32)), dim3(512), 0, stream,
                       Qb, Kb, Vt, Mex, AO);
    hipLaunchKernelGGL(k_proj_ln, dim3(BN / 16), dim3(256), 0, stream,
                       AO, h, Wo, bo, g1, b1l, X, Xb);
    hipLaunchKernelGGL(k_ffn_ln, dim3(BN / 32), dim3(256), 0, stream,
                       X, Xb, W1t, b1, W2t, b2, g2, b2l, out);
}

// Round 8
// 95.594 us; speedup vs baseline: 2.5732x; 1.0716x over previous
//
#include <hip/hip_runtime.h>

#define B_   4
#define N_   2048
#define DIM  128
#define NH   8
#define HD   16
#define FFN_ 256
#define LN_EPS 1e-5f
#define BN   (B_*N_)
#define LOG2E 1.44269504f
#define RESCALE_THR 12.0f   // log2 units

#if __has_builtin(__builtin_amdgcn_exp2f)
#define EXP2(x) __builtin_amdgcn_exp2f(x)
#else
#define EXP2(x) exp2f(x)
#endif

// 1-bit signed extract -> 0 or 0xFFFFFFFF
#if __has_builtin(__builtin_amdgcn_sbfe)
#define SBFE1(w, p) ((unsigned)__builtin_amdgcn_sbfe((int)(w), (p), 1))
#else
#define SBFE1(w, p) ((unsigned)(((int)((w) << (31 - (p)))) >> 31))
#endif

typedef __bf16 bf16x8 __attribute__((ext_vector_type(8)));
typedef short  s16x8  __attribute__((ext_vector_type(8)));
typedef float  f32x16 __attribute__((ext_vector_type(16)));
typedef unsigned int u32x4 __attribute__((ext_vector_type(4)));

template<class T> struct as_short_vec { using type = s16x8; };

template <class T>
__device__ auto mfma_try(T a, T b, f32x16 c, int)
    -> decltype(__builtin_amdgcn_mfma_f32_32x32x16_bf16(a, b, c, 0, 0, 0)) {
  return __builtin_amdgcn_mfma_f32_32x32x16_bf16(a, b, c, 0, 0, 0);
}
template <class T>
__device__ f32x16 mfma_try(T a, T b, f32x16 c, long) {
  return __builtin_amdgcn_mfma_f32_32x32x16_bf16(
      __builtin_bit_cast(typename as_short_vec<T>::type, a),
      __builtin_bit_cast(typename as_short_vec<T>::type, b), c, 0, 0, 0);
}
__device__ __forceinline__ f32x16 mfma_bf(bf16x8 a, bf16x8 b, f32x16 c) {
  return mfma_try(a, b, c, 0);
}

// -------- adj (int32 0/1) -> transposed u32 bit table --------
// adjbT[kc][q], kc = key-block of 32, q = query row. 512 KB, L2-resident.
__global__ __launch_bounds__(256) void k_adjbits(const int* __restrict__ adj,
                                                 unsigned int* __restrict__ adjbT) {
    long long idx = (long long)blockIdx.x * 256 + threadIdx.x;
    int v = adj[idx] != 0;
    unsigned long long m = __ballot(v);
    if ((threadIdx.x & 63) == 0) {
        int q  = (int)(idx >> 11);
        int kc = ((int)idx & 2047) >> 5;   // even; covers kc, kc+1
        adjbT[(size_t)kc * 2048 + q]       = (unsigned)m;
        adjbT[(size_t)(kc + 1) * 2048 + q] = (unsigned)(m >> 32);
    }
}

// ------- cast+transpose FFN weights to bf16, n-major -------
__global__ __launch_bounds__(256) void k_wcast(const float* __restrict__ W1,
                                               const float* __restrict__ W2,
                                               __bf16* __restrict__ W1t,
                                               __bf16* __restrict__ W2t) {
    const int g = blockIdx.x * 256 + threadIdx.x;    // 32768 threads
    {
        int k = g >> 8, n = g & 255;
        W1t[(size_t)n * 128 + k] = (__bf16)W1[(size_t)k * 256 + n];
    }
    {
        int k = g >> 7, n = g & 127;
        W2t[(size_t)n * 256 + k] = (__bf16)W2[(size_t)k * 128 + n];
    }
}

// ---------------- fused QKV projection -> bf16, attention layouts ----------
__global__ __launch_bounds__(512) void k_qkv(const float* __restrict__ h,
    const float* __restrict__ Wq, const float* __restrict__ Wk, const float* __restrict__ Wv,
    __bf16* __restrict__ Qb, __bf16* __restrict__ Kb, __bf16* __restrict__ Vt) {
    __shared__ float hs[32][DIM];
    const int r0  = blockIdx.x * 32;
    const int tid = threadIdx.x;
    for (int i = tid; i < 32 * DIM; i += 512)
        hs[i >> 7][i & 127] = h[(size_t)r0 * DIM + i];
    __syncthreads();
    const int c     = tid & 127;
    const int rbase = (tid >> 7) * 8;
    float aq[8], ak[8], av[8];
    #pragma unroll
    for (int i = 0; i < 8; ++i) { aq[i] = 0.f; ak[i] = 0.f; av[i] = 0.f; }
    for (int k4 = 0; k4 < DIM; k4 += 4) {
        float4 hv[8];
        #pragma unroll
        for (int r = 0; r < 8; ++r) hv[r] = *(const float4*)&hs[rbase + r][k4];
        #pragma unroll
        for (int kk = 0; kk < 4; ++kk) {
            const int k = k4 + kk;
            float wq = Wq[k * DIM + c], wk = Wk[k * DIM + c], wv = Wv[k * DIM + c];
            #pragma unroll
            for (int r = 0; r < 8; ++r) {
                float hvv = ((const float*)&hv[r])[kk];
                aq[r] += hvv * wq; ak[r] += hvv * wk; av[r] += hvv * wv;
            }
        }
    }
    const int hh = c >> 4, d = c & 15;
    const int b  = r0 >> 11;
    const int n0 = (r0 & (N_ - 1)) + rbase;
    size_t qk = ((size_t)(b * NH + hh) * N_ + n0) * HD + d;
    size_t vh = ((size_t)(b * NH + hh) * HD + d) * N_;
    #pragma unroll
    for (int i = 0; i < 8; ++i) {
        Qb[qk + (size_t)i * HD] = (__bf16)(aq[i] * (0.25f * LOG2E));
        Kb[qk + (size_t)i * HD] = (__bf16)ak[i];
        int n  = n0 + i;
        int g  = (n >> 2) & 7;
        int ng = (g & 4) | ((g & 1) << 1) | ((g >> 1) & 1);
        Vt[vh + ((n & ~31) | (ng << 2) | (n & 3))] = (__bf16)av[i];
    }
}

// ---------------- masked flash attention, MFMA 32x32x16, 8-way split-K ----
// grid: B*H*(N/32) = 2048 blocks x 512 thr (8 waves).
// wave kq processes keys [kq*256, kq*256+256) for the block's 32 q-rows.
// Masks come from the 512KB adjbT bit table (L2-resident, coalesced 128B/tile)
// and are expanded in-register (r7 lesson: the 8MB expanded table was 21.5MB
// of scattered HBM traffic = the real bottleneck).
// Do NOT pin launch_bounds min-waves above 4 (r5: VGPR=32 forced, acc spilled).
__global__ __launch_bounds__(512, 4) void k_attn(
    const __bf16* __restrict__ Qb, const __bf16* __restrict__ Kb,
    const __bf16* __restrict__ Vt, const unsigned int* __restrict__ adjbT,
    float* __restrict__ AO) {
    const int bid  = blockIdx.x;
    const int qt   = bid & 63;          // N/32 = 64 q-tiles
    const int hh   = (bid >> 6) & 7;
    const int b    = bid >> 9;
    const int kq   = threadIdx.x >> 6;  // wave = K eighth
    const int lane = threadIdx.x & 63;
    const int l31  = lane & 31, hi = lane >> 5;
    const int q     = qt * 32 + l31;
    const int kbase = kq * 256;
    const int NT    = 8;                // 8 tiles of 32 keys per eighth

    __shared__ float accL[7][64][9];
    __shared__ float mL[8][32], sL[8][32];

    const __bf16* Qh = Qb + (size_t)(b * NH + hh) * N_ * HD;
    const __bf16* Kh = Kb + (size_t)(b * NH + hh) * N_ * HD;
    const __bf16* Vh = Vt + ((size_t)(b * NH + hh) * HD + (l31 & 15)) * N_;
    const unsigned int* wp = adjbT + (size_t)(kq * NT) * 2048 + q;
    const bool vload = (l31 < 16);
    const bf16x8 ones8 = __builtin_bit_cast(bf16x8,
        u32x4{0x3F803F80u, 0x3F803F80u, 0x3F803F80u, 0x3F803F80u});

    bf16x8 qf = *(const bf16x8*)(Qh + (size_t)q * HD + hi * 8);

    f32x16 acc;
    #pragma unroll
    for (int i = 0; i < 16; ++i) acc[i] = 0.f;
    float m = -1e30f;
    const f32x16 z = {};

    bf16x8 kf  = *(const bf16x8*)(Kh + (size_t)(kbase + l31) * HD + hi * 8);
    bf16x8 vfa = vload ? *(const bf16x8*)(Vh + kbase + hi * 8)      : ones8;
    bf16x8 vfb = vload ? *(const bf16x8*)(Vh + kbase + 16 + hi * 8) : ones8;
    unsigned int w32 = wp[0];

    for (int t = 0; t < NT; ++t) {
        // branch-free prefetch of tile t+1 (clamped: last iter re-loads t)
        const int tn = (t + 1 < NT) ? t + 1 : t;
        const int k1 = kbase + tn * 32;
        bf16x8 kf_n = *(const bf16x8*)(Kh + (size_t)(k1 + l31) * HD + hi * 8);
        bf16x8 vfa_n = vload ? *(const bf16x8*)(Vh + k1 + hi * 8)      : ones8;
        bf16x8 vfb_n = vload ? *(const bf16x8*)(Vh + k1 + 16 + hi * 8) : ones8;
        unsigned int w32_n = wp[(size_t)tn * 2048];

        // S^T[k][q] (log2-scaled): D: q = l31, k = (r&3)+8*(r>>2)+4*hi
        f32x16 st = mfma_bf(kf, qf, z);

        float a0 = fmaxf(fmaxf(st[0], st[1]), st[2]);
        float a1 = fmaxf(fmaxf(st[3], st[4]), st[5]);
        float a2 = fmaxf(fmaxf(st[6], st[7]), st[8]);
        float a3 = fmaxf(fmaxf(st[9], st[10]), st[11]);
        float a4 = fmaxf(fmaxf(st[12], st[13]), st[14]);
        float b0 = fmaxf(fmaxf(a0, a1), a2);
        float b1 = fmaxf(fmaxf(a3, a4), st[15]);
        float tm = fmaxf(b0, b1);

        if (__any(tm > m + RESCALE_THR)) {
            float tmj = fmaxf(tm, __shfl_xor(tm, 32));
            float mn  = fmaxf(m, tmj);
            float sc  = EXP2(m - mn);
            #pragma unroll
            for (int r = 0; r < 9; ++r) acc[r] *= sc;
            m = mn;
        }

        float p[16];
        #pragma unroll
        for (int r = 0; r < 16; ++r) p[r] = EXP2(st[r] - m);
        bf16x8 pa, pb;
        #pragma unroll
        for (int r = 0; r < 8; ++r) { pa[r] = (__bf16)p[r]; pb[r] = (__bf16)p[r + 8]; }

        // expand mask bits -> packed-bf16 AND masks, in-register.
        // word j of pa covers keys pos(2j)=pbase[j]+4*hi and pos(2j)+1;
        // pb the same + 16. pbase = {0,2,8,10,16,18,24,26}.
        {
            const unsigned ws = w32 >> (4 * hi);
            u32x4 mA0, mB0;
            #pragma unroll
            for (int j = 0; j < 4; ++j) {
                const int pbase = (2 * j) & 3 ? 2 : (j >= 2 ? 8 : 0);
                const int pj = ((2 * j) & 3) + 8 * ((2 * j) >> 2);   // 0,2,8,10
                mA0[j] = (SBFE1(ws, pj)      & 0xFFFFu) | (SBFE1(ws, pj + 1)  & 0xFFFF0000u);
                mB0[j] = (SBFE1(ws, pj + 16) & 0xFFFFu) | (SBFE1(ws, pj + 17) & 0xFFFF0000u);
                (void)pbase;
            }
            u32x4 mA1, mB1;
            #pragma unroll
            for (int j = 0; j < 4; ++j) {
                const int pj = ((2 * j) & 3) + 8 * ((2 * j) >> 2) + 4;  // 4,6,12,14
                mA1[j] = (SBFE1(ws, pj)      & 0xFFFFu) | (SBFE1(ws, pj + 1)  & 0xFFFF0000u);
                mB1[j] = (SBFE1(ws, pj + 16) & 0xFFFFu) | (SBFE1(ws, pj + 17) & 0xFFFF0000u);
            }
            // pa words 0..3 use r=0..7 -> pos pbase[0..3]; words of pa are
            // r pairs (0,1),(2,3),(4,5),(6,7) -> pos (r&3)+8*(r>>2): 0,2,8,10 = mA0
            // wait: r=4 -> (4&3)+8*(4>>2)=0+8=8 ✓ handled by mA0[2]; r=2 -> 2 ✓
            // pb words use r=8..15 -> pos +16 of the same sequence = mB0.
            pa = __builtin_bit_cast(bf16x8, __builtin_bit_cast(u32x4, pa) & mA0);
            pb = __builtin_bit_cast(bf16x8, __builtin_bit_cast(u32x4, pb) & mB0);
            (void)mA1; (void)mB1;
        }

        // PV; A rows 16..31 are register-ones -> acc[8] accumulates sum(p)
        acc = mfma_bf(vfa, pa, acc);
        acc = mfma_bf(vfb, pb, acc);

        kf = kf_n; vfa = vfa_n; vfb = vfb_n; w32 = w32_n;
    }

    const float sum = acc[8];

    // ---- 8-way split-K merge through LDS ----
    if (kq != 0) {
        #pragma unroll
        for (int r = 0; r < 8; ++r) accL[kq - 1][lane][r] = acc[r];
    }
    if (hi == 0) { mL[kq][l31] = m; sL[kq][l31] = sum; }
    __syncthreads();
    if (kq == 0) {
        float M = m;
        #pragma unroll
        for (int i = 1; i < 8; ++i) M = fmaxf(M, mL[i][l31]);
        float e0 = EXP2(m - M);
        float s  = sum * e0;
        float e[7];
        #pragma unroll
        for (int i = 0; i < 7; ++i) {
            e[i] = EXP2(mL[i + 1][l31] - M);
            s += sL[i + 1][l31] * e[i];
        }
        float inv = 1.f / s;
        float o[8];
        #pragma unroll
        for (int r = 0; r < 8; ++r) {
            float v = acc[r] * e0;
            #pragma unroll
            for (int i = 0; i < 7; ++i) v += accL[i][lane][r] * e[i];
            o[r] = v * inv;
        }
        float* op = AO + ((size_t)(b * N_ + q)) * DIM + hh * HD + 4 * hi;
        float4 o0 = { o[0], o[1], o[2], o[3] };
        float4 o1 = { o[4], o[5], o[6], o[7] };
        *(float4*)op       = o0;
        *(float4*)(op + 8) = o1;
    }
}

// ---------------- Wo projection + residual + LN1 (also emits bf16 X) ------
__global__ __launch_bounds__(256) void k_proj_ln(
    const float* __restrict__ AO, const float* __restrict__ h,
    const float* __restrict__ Wo, const float* __restrict__ bo,
    const float* __restrict__ g, const float* __restrict__ bln,
    float* __restrict__ X, __bf16* __restrict__ Xb) {
    const int r0  = blockIdx.x * 16;
    const int tid = threadIdx.x;
    __shared__ float a[16][DIM];
    __shared__ float vv[16][DIM];
    __shared__ float mu_s[16], rs_s[16];
    for (int i = tid; i < 16 * DIM; i += 256)
        a[i >> 7][i & 127] = AO[(size_t)r0 * DIM + i];
    __syncthreads();
    const int c = tid & 127, rg = tid >> 7;
    float accv[8];
    float bov = bo[c];
    #pragma unroll
    for (int r = 0; r < 8; ++r) accv[r] = bov;
    for (int k = 0; k < DIM; ++k) {
        float w = Wo[k * DIM + c];
        #pragma unroll
        for (int r = 0; r < 8; ++r) accv[r] += a[rg * 8 + r][k] * w;
    }
    #pragma unroll
    for (int r = 0; r < 8; ++r)
        vv[rg * 8 + r][c] = accv[r] + h[((size_t)(r0 + rg * 8 + r)) * DIM + c];
    __syncthreads();
    const int wvx = tid >> 6, ln = tid & 63;
    #pragma unroll
    for (int i = 0; i < 4; ++i) {
        int r = wvx * 4 + i;
        float x0 = vv[r][ln], x1 = vv[r][ln + 64];
        float s = x0 + x1, s2 = x0 * x0 + x1 * x1;
        for (int off = 1; off < 64; off <<= 1) {
            s  += __shfl_xor(s,  off);
            s2 += __shfl_xor(s2, off);
        }
        if (ln == 0) {
            float mu = s * (1.f / DIM);
            float var = s2 * (1.f / DIM) - mu * mu;
            mu_s[r] = mu; rs_s[r] = rsqrtf(var + LN_EPS);
        }
    }
    __syncthreads();
    float gc = g[c], bc = bln[c];
    #pragma unroll
    for (int r = 0; r < 8; ++r) {
        int rr = rg * 8 + r;
        float val = (vv[rr][c] - mu_s[rr]) * rs_s[rr] * gc + bc;
        size_t o = ((size_t)(r0 + rr)) * DIM + c;
        X[o]  = val;
        Xb[o] = (__bf16)val;
    }
}

// ---------------- FFN + residual + LN2, MFMA ----------------
__global__ __launch_bounds__(256) void k_ffn_ln(
    const float* __restrict__ X, const __bf16* __restrict__ Xb,
    const __bf16* __restrict__ W1t, const float* __restrict__ b1,
    const __bf16* __restrict__ W2t, const float* __restrict__ b2,
    const float* __restrict__ g, const float* __restrict__ bln,
    float* __restrict__ out) {
    const int r0   = blockIdx.x * 32;
    const int tid  = threadIdx.x;
    const int w    = tid >> 6;
    const int lane = tid & 63;
    const int l31  = lane & 31, hi = lane >> 5;

    __shared__ __bf16 Xs[32 * 128];   // XOR-swizzled: byte ^= (row&7)<<4
    __shared__ __bf16 Ts[32 * 256];   // XOR-swizzled: byte ^= (row&7)<<4
    __shared__ float  vv[32][DIM];

    for (int i = tid; i < 512; i += 256) {
        int row = i >> 4, u = i & 15;
        bf16x8 v = *(const bf16x8*)(Xb + (size_t)(r0 + row) * DIM + u * 8);
        int byte = (row * 256 + u * 16) ^ ((row & 7) << 4);
        *(bf16x8*)((char*)Xs + byte) = v;
    }
    __syncthreads();

    f32x16 acc1a, acc1b;
    #pragma unroll
    for (int i = 0; i < 16; ++i) { acc1a[i] = 0.f; acc1b[i] = 0.f; }
    #pragma unroll
    for (int kk = 0; kk < 8; ++kk) {
        int byte = (l31 * 256 + kk * 32 + hi * 16) ^ ((l31 & 7) << 4);
        bf16x8 a = *(const bf16x8*)((const char*)Xs + byte);
        bf16x8 bA = *(const bf16x8*)(W1t + (size_t)(w * 32 + l31) * 128 + kk * 16 + hi * 8);
        bf16x8 bB = *(const bf16x8*)(W1t + (size_t)((w + 4) * 32 + l31) * 128 + kk * 16 + hi * 8);
        acc1a = mfma_bf(a, bA, acc1a);
        acc1b = mfma_bf(a, bB, acc1b);
    }
    #pragma unroll
    for (int ct = 0; ct < 2; ++ct) {
        const f32x16& ac = ct ? acc1b : acc1a;
        int n = (w + ct * 4) * 32 + l31;
        float bb = b1[n];
        #pragma unroll
        for (int r = 0; r < 16; ++r) {
            int mm = (r & 3) + 8 * (r >> 2) + 4 * hi;
            float v = fmaxf(ac[r] + bb, 0.f);
            int byte = (mm * 512 + n * 2) ^ ((mm & 7) << 4);
            *(__bf16*)((char*)Ts + byte) = (__bf16)v;
        }
    }
    __syncthreads();

    f32x16 acc2;
    #pragma unroll
    for (int i = 0; i < 16; ++i) acc2[i] = 0.f;
    #pragma unroll
    for (int kk = 0; kk < 16; ++kk) {
        int byte = (l31 * 512 + kk * 32 + hi * 16) ^ ((l31 & 7) << 4);
        bf16x8 a = *(const bf16x8*)((const char*)Ts + byte);
        bf16x8 bb = *(const bf16x8*)(W2t + (size_t)(w * 32 + l31) * 256 + kk * 16 + hi * 8);
        acc2 = mfma_bf(a, bb, acc2);
    }
    {
        int n = w * 32 + l31;
        float bb = b2[n];
        #pragma unroll
        for (int r = 0; r < 16; ++r) {
            int mm = (r & 3) + 8 * (r >> 2) + 4 * hi;
            vv[mm][n] = acc2[r] + bb + X[(size_t)(r0 + mm) * DIM + n];
        }
    }
    __syncthreads();

    const int ln = lane;
    float gc0 = g[ln], bc0 = bln[ln], gc1 = g[ln + 64], bc1 = bln[ln + 64];
    #pragma unroll
    for (int i = 0; i < 8; ++i) {
        int rr = w * 8 + i;
        float x0 = vv[rr][ln], x1 = vv[rr][ln + 64];
        float s = x0 + x1, s2 = x0 * x0 + x1 * x1;
        for (int off = 1; off < 64; off <<= 1) {
            s  += __shfl_xor(s,  off);
            s2 += __shfl_xor(s2, off);
        }
        float mu  = s * (1.f / DIM);
        float var = s2 * (1.f / DIM) - mu * mu;
        float rs  = rsqrtf(var + LN_EPS);
        size_t o = (size_t)(r0 + rr) * DIM;
        out[o + ln]      = (x0 - mu) * rs * gc0 + bc0;
        out[o + ln + 64] = (x1 - mu) * rs * gc1 + bc1;
    }
}

extern "C" void kernel_launch(void* const* d_in, const int* in_sizes, int n_in,
                              void* d_out, int out_size, void* d_ws, size_t ws_size,
                              hipStream_t stream) {
    const int*   adj = (const int*)  d_in[0];
    const float* h   = (const float*)d_in[1];
    const float* Wq  = (const float*)d_in[2];
    const float* Wk  = (const float*)d_in[3];
    const float* Wv  = (const float*)d_in[4];
    const float* Wo  = (const float*)d_in[5];
    const float* bo  = (const float*)d_in[6];
    const float* g1  = (const float*)d_in[7];
    const float* b1l = (const float*)d_in[8];
    const float* W1  = (const float*)d_in[9];
    const float* b1  = (const float*)d_in[10];
    const float* W2  = (const float*)d_in[11];
    const float* b2  = (const float*)d_in[12];
    const float* g2  = (const float*)d_in[13];
    const float* b2l = (const float*)d_in[14];
    float* out = (float*)d_out;

    float* AO = (float*)d_ws;                                  // 4MB
    float* X  = AO + (size_t)BN * DIM;                         // 4MB
    unsigned int* adjbT = (unsigned int*)(X + (size_t)BN * DIM);   // 512KB
    __bf16* Qb  = (__bf16*)(adjbT + (size_t)64 * 2048);        // 2MB
    __bf16* Kb  = Qb + (size_t)BN * DIM;                       // 2MB
    __bf16* Vt  = Kb + (size_t)BN * DIM;                       // 2MB
    __bf16* Xb  = Vt + (size_t)BN * DIM;                       // 2MB
    __bf16* W1t = Xb + (size_t)BN * DIM;                       // 64KB
    __bf16* W2t = W1t + (size_t)DIM * FFN_;                    // 64KB

    hipLaunchKernelGGL(k_adjbits, dim3(N_ * N_ / 256), dim3(256), 0, stream, adj, adjbT);
    hipLaunchKernelGGL(k_wcast, dim3(128), dim3(256), 0, stream, W1, W2, W1t, W2t);
    hipLaunchKernelGGL(k_qkv, dim3(BN / 32), dim3(512), 0, stream, h, Wq, Wk, Wv, Qb, Kb, Vt);
    hipLaunchKernelGGL(k_attn, dim3(B_ * NH * (N_ / 32)), dim3(512), 0, stream,
                       Qb, Kb, Vt, adjbT, AO);
    hipLaunchKernelGGL(k_proj_ln, dim3(BN / 16), dim3(256), 0, stream,
                       AO, h, Wo, bo, g1, b1l, X, Xb);
    hipLaunchKernelGGL(k_ffn_ln, dim3(BN / 32), dim3(256), 0, stream,
                       X, Xb, W1t, b1, W2t, b2, g2, b2l, out);
}

// Round 9
// 71.777 us; speedup vs baseline: 3.4270x; 1.3318x over previous
//
#include <hip/hip_runtime.h>

#define B_   4
#define N_   2048
#define DIM  128
#define NH   8
#define HD   16
#define FFN_ 256
#define LN_EPS 1e-5f
#define BN   (B_*N_)
#define LOG2E 1.44269504f

#if __has_builtin(__builtin_amdgcn_exp2f)
#define EXP2(x) __builtin_amdgcn_exp2f(x)
#else
#define EXP2(x) exp2f(x)
#endif

// 1-bit signed extract -> 0 or 0xFFFFFFFF
#if __has_builtin(__builtin_amdgcn_sbfe)
#define SBFE1(w, p) ((unsigned)__builtin_amdgcn_sbfe((int)(w), (p), 1))
#else
#define SBFE1(w, p) ((unsigned)(((int)((w) << (31 - (p)))) >> 31))
#endif

typedef __bf16 bf16x8 __attribute__((ext_vector_type(8)));
typedef short  s16x8  __attribute__((ext_vector_type(8)));
typedef float  f32x16 __attribute__((ext_vector_type(16)));
typedef unsigned int u32x4 __attribute__((ext_vector_type(4)));

template<class T> struct as_short_vec { using type = s16x8; };

template <class T>
__device__ auto mfma_try(T a, T b, f32x16 c, int)
    -> decltype(__builtin_amdgcn_mfma_f32_32x32x16_bf16(a, b, c, 0, 0, 0)) {
  return __builtin_amdgcn_mfma_f32_32x32x16_bf16(a, b, c, 0, 0, 0);
}
template <class T>
__device__ f32x16 mfma_try(T a, T b, f32x16 c, long) {
  return __builtin_amdgcn_mfma_f32_32x32x16_bf16(
      __builtin_bit_cast(typename as_short_vec<T>::type, a),
      __builtin_bit_cast(typename as_short_vec<T>::type, b), c, 0, 0, 0);
}
__device__ __forceinline__ f32x16 mfma_bf(bf16x8 a, bf16x8 b, f32x16 c) {
  return mfma_try(a, b, c, 0);
}

// -------- adj (int32 0/1) -> transposed u32 bit table --------
// adjbT[kc][q], kc = key-block of 32, q = query row. 512 KB, L2-resident.
__global__ __launch_bounds__(256) void k_adjbits(const int* __restrict__ adj,
                                                 unsigned int* __restrict__ adjbT) {
    long long idx = (long long)blockIdx.x * 256 + threadIdx.x;
    int v = adj[idx] != 0;
    unsigned long long m = __ballot(v);
    if ((threadIdx.x & 63) == 0) {
        int q  = (int)(idx >> 11);
        int kc = ((int)idx & 2047) >> 5;   // even; covers kc, kc+1
        adjbT[(size_t)kc * 2048 + q]       = (unsigned)m;
        adjbT[(size_t)(kc + 1) * 2048 + q] = (unsigned)(m >> 32);
    }
}

// ------- cast+transpose all weights to bf16, n-major -------
// Q-scale (0.25*log2e) folded into Wqt.
__global__ __launch_bounds__(256) void k_wcast(
    const float* __restrict__ W1, const float* __restrict__ W2,
    const float* __restrict__ Wq, const float* __restrict__ Wk,
    const float* __restrict__ Wv, const float* __restrict__ Wo,
    __bf16* __restrict__ W1t, __bf16* __restrict__ W2t,
    __bf16* __restrict__ Wqt, __bf16* __restrict__ Wkt,
    __bf16* __restrict__ Wvt, __bf16* __restrict__ Wot) {
    const int g = blockIdx.x * 256 + threadIdx.x;    // 32768 threads
    {
        int k = g >> 8, n = g & 255;
        W1t[(size_t)n * 128 + k] = (__bf16)W1[(size_t)k * 256 + n];
    }
    {
        int k = g >> 7, n = g & 127;
        W2t[(size_t)n * 256 + k] = (__bf16)W2[(size_t)k * 128 + n];
    }
    if (g < 16384) {
        int k = g >> 7, n = g & 127;
        size_t s = (size_t)k * 128 + n, d = (size_t)n * 128 + k;
        Wqt[d] = (__bf16)(Wq[s] * (0.25f * LOG2E));
        Wkt[d] = (__bf16)Wk[s];
        Wvt[d] = (__bf16)Wv[s];
        Wot[d] = (__bf16)Wo[s];
    }
}

// ------- h -> bf16 -------
__global__ __launch_bounds__(256) void k_hcast(const float* __restrict__ h,
                                               __bf16* __restrict__ hb) {
    const int g = blockIdx.x * 256 + threadIdx.x;   // BN*DIM/8 threads
    const float* src = h + (size_t)g * 8;
    float4 f0 = *(const float4*)src, f1 = *(const float4*)(src + 4);
    bf16x8 v;
    v[0] = (__bf16)f0.x; v[1] = (__bf16)f0.y; v[2] = (__bf16)f0.z; v[3] = (__bf16)f0.w;
    v[4] = (__bf16)f1.x; v[5] = (__bf16)f1.y; v[6] = (__bf16)f1.z; v[7] = (__bf16)f1.w;
    *(bf16x8*)(hb + (size_t)g * 8) = v;
}

// ---------------- QKV projection, MFMA ----------------
// grid BN/32 = 256 blocks x 256 thr (4 waves). Wave w -> out cols [w*32,w*32+32).
// Qb,Kb: [B][H][N][HD] bf16 (Q pre-scaled via Wqt); Vt: [B][H][16][N] key-permuted.
__global__ __launch_bounds__(256) void k_qkv(
    const __bf16* __restrict__ hb,
    const __bf16* __restrict__ Wqt, const __bf16* __restrict__ Wkt,
    const __bf16* __restrict__ Wvt,
    __bf16* __restrict__ Qb, __bf16* __restrict__ Kb, __bf16* __restrict__ Vt) {
    const int r0   = blockIdx.x * 32;
    const int tid  = threadIdx.x;
    const int w    = tid >> 6;
    const int lane = tid & 63;
    const int l31  = lane & 31, hi = lane >> 5;

    __shared__ __bf16 Hs[32 * 128];   // XOR-swizzled: byte ^= (row&7)<<4

    for (int i = tid; i < 512; i += 256) {
        int row = i >> 4, u = i & 15;
        bf16x8 v = *(const bf16x8*)(hb + (size_t)(r0 + row) * DIM + u * 8);
        int byte = (row * 256 + u * 16) ^ ((row & 7) << 4);
        *(bf16x8*)((char*)Hs + byte) = v;
    }
    __syncthreads();

    f32x16 aq, ak, av;
    #pragma unroll
    for (int i = 0; i < 16; ++i) { aq[i] = 0.f; ak[i] = 0.f; av[i] = 0.f; }
    #pragma unroll
    for (int kk = 0; kk < 8; ++kk) {
        int byte = (l31 * 256 + kk * 32 + hi * 16) ^ ((l31 & 7) << 4);
        bf16x8 a = *(const bf16x8*)((const char*)Hs + byte);
        const size_t wo = (size_t)(w * 32 + l31) * 128 + kk * 16 + hi * 8;
        aq = mfma_bf(a, *(const bf16x8*)(Wqt + wo), aq);
        ak = mfma_bf(a, *(const bf16x8*)(Wkt + wo), ak);
        av = mfma_bf(a, *(const bf16x8*)(Wvt + wo), av);
    }
    const int n  = w * 32 + l31;           // output col 0..127
    const int hh = n >> 4, d = n & 15;
    const int b  = r0 >> 11;
    const size_t qbase = (size_t)(b * NH + hh) * N_;
    const size_t vbase = ((size_t)(b * NH + hh) * HD + d) * N_;
    #pragma unroll
    for (int r = 0; r < 16; ++r) {
        int mm   = (r & 3) + 8 * (r >> 2) + 4 * hi;
        int nloc = (r0 & (N_ - 1)) + mm;
        size_t qk = (qbase + nloc) * HD + d;
        Qb[qk] = (__bf16)aq[r];
        Kb[qk] = (__bf16)ak[r];
        int gg = (nloc >> 2) & 7;
        int ng = (gg & 4) | ((gg & 1) << 1) | ((gg >> 1) & 1);
        Vt[vbase + ((nloc & ~31) | (ng << 2) | (nloc & 3))] = (__bf16)av[r];
    }
}

// ---------------- masked flash attention, MFMA, fixed-max softmax ----------
// grid: B*H*(N/32) = 2048 blocks x 512 thr (8 waves); wave kq = 256-key eighth.
// Fixed max (m=0): st = 0.25*log2e*(Q.K) has sigma~0.5, |st|>8 is >16-sigma —
// p = 2^st in [2^-8, 2^8], no overflow, bf16 relative precision unchanged.
// Kills max-tree/rescale/m-merge; split-K merge is a pure sum (sum = acc[8]).
// Do NOT pin launch_bounds min-waves above 4 (r5: VGPR=32 forced, acc spilled).
__global__ __launch_bounds__(512, 4) void k_attn(
    const __bf16* __restrict__ Qb, const __bf16* __restrict__ Kb,
    const __bf16* __restrict__ Vt, const unsigned int* __restrict__ adjbT,
    float* __restrict__ AO) {
    const int bid  = blockIdx.x;
    const int qt   = bid & 63;          // N/32 = 64 q-tiles
    const int hh   = (bid >> 6) & 7;
    const int b    = bid >> 9;
    const int kq   = threadIdx.x >> 6;  // wave = K eighth
    const int lane = threadIdx.x & 63;
    const int l31  = lane & 31, hi = lane >> 5;
    const int q     = qt * 32 + l31;
    const int kbase = kq * 256;
    const int NT    = 8;                // 8 tiles of 32 keys per eighth

    __shared__ float accL[7][64][9];

    const __bf16* Qh = Qb + (size_t)(b * NH + hh) * N_ * HD;
    const __bf16* Kh = Kb + (size_t)(b * NH + hh) * N_ * HD;
    const __bf16* Vh = Vt + ((size_t)(b * NH + hh) * HD + (l31 & 15)) * N_;
    const unsigned int* wp = adjbT + (size_t)(kq * NT) * 2048 + q;
    const bool vload = (l31 < 16);
    const bf16x8 ones8 = __builtin_bit_cast(bf16x8,
        u32x4{0x3F803F80u, 0x3F803F80u, 0x3F803F80u, 0x3F803F80u});

    bf16x8 qf = *(const bf16x8*)(Qh + (size_t)q * HD + hi * 8);

    f32x16 acc;
    #pragma unroll
    for (int i = 0; i < 16; ++i) acc[i] = 0.f;
    const f32x16 z = {};

    bf16x8 kf  = *(const bf16x8*)(Kh + (size_t)(kbase + l31) * HD + hi * 8);
    bf16x8 vfa = vload ? *(const bf16x8*)(Vh + kbase + hi * 8)      : ones8;
    bf16x8 vfb = vload ? *(const bf16x8*)(Vh + kbase + 16 + hi * 8) : ones8;
    unsigned int w32 = wp[0];

    for (int t = 0; t < NT; ++t) {
        // branch-free prefetch of tile t+1 (clamped: last iter re-loads t)
        const int tn = (t + 1 < NT) ? t + 1 : t;
        const int k1 = kbase + tn * 32;
        bf16x8 kf_n = *(const bf16x8*)(Kh + (size_t)(k1 + l31) * HD + hi * 8);
        bf16x8 vfa_n = vload ? *(const bf16x8*)(Vh + k1 + hi * 8)      : ones8;
        bf16x8 vfb_n = vload ? *(const bf16x8*)(Vh + k1 + 16 + hi * 8) : ones8;
        unsigned int w32_n = wp[(size_t)tn * 2048];

        // S^T[k][q] (log2-scaled): D: q = l31, k = (r&3)+8*(r>>2)+4*hi
        f32x16 st = mfma_bf(kf, qf, z);

        // p = 2^st (fixed max), mask applied on packed bf16 via AND
        float p[16];
        #pragma unroll
        for (int r = 0; r < 16; ++r) p[r] = EXP2(st[r]);
        bf16x8 pa, pb;
        #pragma unroll
        for (int r = 0; r < 8; ++r) { pa[r] = (__bf16)p[r]; pb[r] = (__bf16)p[r + 8]; }

        // expand mask bits -> packed-bf16 AND masks (word j of pa covers key
        // positions pj, pj+1 with pj = (2j&3)+8*(2j>>2)+4*hi; pb same +16)
        {
            const unsigned ws = w32 >> (4 * hi);
            u32x4 mA, mB;
            #pragma unroll
            for (int j = 0; j < 4; ++j) {
                const int pj = ((2 * j) & 3) + 8 * ((2 * j) >> 2);   // 0,2,8,10
                mA[j] = (SBFE1(ws, pj)      & 0xFFFFu) | (SBFE1(ws, pj + 1)  & 0xFFFF0000u);
                mB[j] = (SBFE1(ws, pj + 16) & 0xFFFFu) | (SBFE1(ws, pj + 17) & 0xFFFF0000u);
            }
            pa = __builtin_bit_cast(bf16x8, __builtin_bit_cast(u32x4, pa) & mA);
            pb = __builtin_bit_cast(bf16x8, __builtin_bit_cast(u32x4, pb) & mB);
        }

        // PV; A rows 16..31 are register-ones -> acc[8] accumulates sum(p)
        acc = mfma_bf(vfa, pa, acc);
        acc = mfma_bf(vfb, pb, acc);

        kf = kf_n; vfa = vfa_n; vfb = vfb_n; w32 = w32_n;
    }

    // ---- 8-way split-K merge: pure sums (no max bookkeeping) ----
    if (kq != 0) {
        #pragma unroll
        for (int r = 0; r < 9; ++r) accL[kq - 1][lane][r] = acc[r];
    }
    __syncthreads();
    if (kq == 0) {
        float tot[9];
        #pragma unroll
        for (int r = 0; r < 9; ++r) {
            float v = acc[r];
            #pragma unroll
            for (int i = 0; i < 7; ++i) v += accL[i][lane][r];
            tot[r] = v;
        }
        float inv = 1.f / tot[8];
        float* op = AO + ((size_t)(b * N_ + q)) * DIM + hh * HD + 4 * hi;
        float4 o0 = { tot[0] * inv, tot[1] * inv, tot[2] * inv, tot[3] * inv };
        float4 o1 = { tot[4] * inv, tot[5] * inv, tot[6] * inv, tot[7] * inv };
        *(float4*)op       = o0;   // d = 4*hi + 0..3
        *(float4*)(op + 8) = o1;   // d = 8 + 4*hi + 0..3
    }
}

// ---------------- Wo projection + residual + LN1, MFMA ----------------
// grid BN/32 = 256 blocks x 256 thr. Emits X fp32 + Xb bf16 (for FFN).
__global__ __launch_bounds__(256) void k_proj_ln(
    const float* __restrict__ AO, const float* __restrict__ h,
    const __bf16* __restrict__ Wot, const float* __restrict__ bo,
    const float* __restrict__ g, const float* __restrict__ bln,
    float* __restrict__ X, __bf16* __restrict__ Xb) {
    const int r0   = blockIdx.x * 32;
    const int tid  = threadIdx.x;
    const int w    = tid >> 6;
    const int lane = tid & 63;
    const int l31  = lane & 31, hi = lane >> 5;

    __shared__ __bf16 As[32 * 128];   // XOR-swizzled
    __shared__ float  vv[32][DIM];

    for (int i = tid; i < 512; i += 256) {
        int row = i >> 4, u = i & 15;
        const float* src = AO + (size_t)(r0 + row) * DIM + u * 8;
        float4 f0 = *(const float4*)src, f1 = *(const float4*)(src + 4);
        bf16x8 v;
        v[0] = (__bf16)f0.x; v[1] = (__bf16)f0.y; v[2] = (__bf16)f0.z; v[3] = (__bf16)f0.w;
        v[4] = (__bf16)f1.x; v[5] = (__bf16)f1.y; v[6] = (__bf16)f1.z; v[7] = (__bf16)f1.w;
        int byte = (row * 256 + u * 16) ^ ((row & 7) << 4);
        *(bf16x8*)((char*)As + byte) = v;
    }
    __syncthreads();

    f32x16 acc;
    #pragma unroll
    for (int i = 0; i < 16; ++i) acc[i] = 0.f;
    #pragma unroll
    for (int kk = 0; kk < 8; ++kk) {
        int byte = (l31 * 256 + kk * 32 + hi * 16) ^ ((l31 & 7) << 4);
        bf16x8 a = *(const bf16x8*)((const char*)As + byte);
        acc = mfma_bf(a, *(const bf16x8*)(Wot + (size_t)(w * 32 + l31) * 128 + kk * 16 + hi * 8), acc);
    }
    {
        int n = w * 32 + l31;
        float bb = bo[n];
        #pragma unroll
        for (int r = 0; r < 16; ++r) {
            int mm = (r & 3) + 8 * (r >> 2) + 4 * hi;
            vv[mm][n] = acc[r] + bb + h[(size_t)(r0 + mm) * DIM + n];
        }
    }
    __syncthreads();

    const int ln = lane;
    float gc0 = g[ln], bc0 = bln[ln], gc1 = g[ln + 64], bc1 = bln[ln + 64];
    #pragma unroll
    for (int i = 0; i < 8; ++i) {
        int rr = w * 8 + i;
        float x0 = vv[rr][ln], x1 = vv[rr][ln + 64];
        float s = x0 + x1, s2 = x0 * x0 + x1 * x1;
        for (int off = 1; off < 64; off <<= 1) {
            s  += __shfl_xor(s,  off);
            s2 += __shfl_xor(s2, off);
        }
        float mu  = s * (1.f / DIM);
        float var = s2 * (1.f / DIM) - mu * mu;
        float rs  = rsqrtf(var + LN_EPS);
        float v0 = (x0 - mu) * rs * gc0 + bc0;
        float v1 = (x1 - mu) * rs * gc1 + bc1;
        size_t o = (size_t)(r0 + rr) * DIM;
        X[o + ln]       = v0;
        X[o + ln + 64]  = v1;
        Xb[o + ln]      = (__bf16)v0;
        Xb[o + ln + 64] = (__bf16)v1;
    }
}

// ---------------- FFN + residual + LN2, MFMA ----------------
__global__ __launch_bounds__(256) void k_ffn_ln(
    const float* __restrict__ X, const __bf16* __restrict__ Xb,
    const __bf16* __restrict__ W1t, const float* __restrict__ b1,
    const __bf16* __restrict__ W2t, const float* __restrict__ b2,
    const float* __restrict__ g, const float* __restrict__ bln,
    float* __restrict__ out) {
    const int r0   = blockIdx.x * 32;
    const int tid  = threadIdx.x;
    const int w    = tid >> 6;
    const int lane = tid & 63;
    const int l31  = lane & 31, hi = lane >> 5;

    __shared__ __bf16 Xs[32 * 128];   // XOR-swizzled
    __shared__ __bf16 Ts[32 * 256];   // XOR-swizzled
    __shared__ float  vv[32][DIM];

    for (int i = tid; i < 512; i += 256) {
        int row = i >> 4, u = i & 15;
        bf16x8 v = *(const bf16x8*)(Xb + (size_t)(r0 + row) * DIM + u * 8);
        int byte = (row * 256 + u * 16) ^ ((row & 7) << 4);
        *(bf16x8*)((char*)Xs + byte) = v;
    }
    __syncthreads();

    f32x16 acc1a, acc1b;
    #pragma unroll
    for (int i = 0; i < 16; ++i) { acc1a[i] = 0.f; acc1b[i] = 0.f; }
    #pragma unroll
    for (int kk = 0; kk < 8; ++kk) {
        int byte = (l31 * 256 + kk * 32 + hi * 16) ^ ((l31 & 7) << 4);
        bf16x8 a = *(const bf16x8*)((const char*)Xs + byte);
        bf16x8 bA = *(const bf16x8*)(W1t + (size_t)(w * 32 + l31) * 128 + kk * 16 + hi * 8);
        bf16x8 bB = *(const bf16x8*)(W1t + (size_t)((w + 4) * 32 + l31) * 128 + kk * 16 + hi * 8);
        acc1a = mfma_bf(a, bA, acc1a);
        acc1b = mfma_bf(a, bB, acc1b);
    }
    #pragma unroll
    for (int ct = 0; ct < 2; ++ct) {
        const f32x16& ac = ct ? acc1b : acc1a;
        int n = (w + ct * 4) * 32 + l31;
        float bb = b1[n];
        #pragma unroll
        for (int r = 0; r < 16; ++r) {
            int mm = (r & 3) + 8 * (r >> 2) + 4 * hi;
            float v = fmaxf(ac[r] + bb, 0.f);
            int byte = (mm * 512 + n * 2) ^ ((mm & 7) << 4);
            *(__bf16*)((char*)Ts + byte) = (__bf16)v;
        }
    }
    __syncthreads();

    f32x16 acc2;
    #pragma unroll
    for (int i = 0; i < 16; ++i) acc2[i] = 0.f;
    #pragma unroll
    for (int kk = 0; kk < 16; ++kk) {
        int byte = (l31 * 512 + kk * 32 + hi * 16) ^ ((l31 & 7) << 4);
        bf16x8 a = *(const bf16x8*)((const char*)Ts + byte);
        bf16x8 bb = *(const bf16x8*)(W2t + (size_t)(w * 32 + l31) * 256 + kk * 16 + hi * 8);
        acc2 = mfma_bf(a, bb, acc2);
    }
    {
        int n = w * 32 + l31;
        float bb = b2[n];
        #pragma unroll
        for (int r = 0; r < 16; ++r) {
            int mm = (r & 3) + 8 * (r >> 2) + 4 * hi;
            vv[mm][n] = acc2[r] + bb + X[(size_t)(r0 + mm) * DIM + n];
        }
    }
    __syncthreads();

    const int ln = lane;
    float gc0 = g[ln], bc0 = bln[ln], gc1 = g[ln + 64], bc1 = bln[ln + 64];
    #pragma unroll
    for (int i = 0; i < 8; ++i) {
        int rr = w * 8 + i;
        float x0 = vv[rr][ln], x1 = vv[rr][ln + 64];
        float s = x0 + x1, s2 = x0 * x0 + x1 * x1;
        for (int off = 1; off < 64; off <<= 1) {
            s  += __shfl_xor(s,  off);
            s2 += __shfl_xor(s2, off);
        }
        float mu  = s * (1.f / DIM);
        float var = s2 * (1.f / DIM) - mu * mu;
        float rs  = rsqrtf(var + LN_EPS);
        size_t o = (size_t)(r0 + rr) * DIM;
        out[o + ln]      = (x0 - mu) * rs * gc0 + bc0;
        out[o + ln + 64] = (x1 - mu) * rs * gc1 + bc1;
    }
}

extern "C" void kernel_launch(void* const* d_in, const int* in_sizes, int n_in,
                              void* d_out, int out_size, void* d_ws, size_t ws_size,
                              hipStream_t stream) {
    const int*   adj = (const int*)  d_in[0];
    const float* h   = (const float*)d_in[1];
    const float* Wq  = (const float*)d_in[2];
    const float* Wk  = (const float*)d_in[3];
    const float* Wv  = (const float*)d_in[4];
    const float* Wo  = (const float*)d_in[5];
    const float* bo  = (const float*)d_in[6];
    const float* g1  = (const float*)d_in[7];
    const float* b1l = (const float*)d_in[8];
    const float* W1  = (const float*)d_in[9];
    const float* b1  = (const float*)d_in[10];
    const float* W2  = (const float*)d_in[11];
    const float* b2  = (const float*)d_in[12];
    const float* g2  = (const float*)d_in[13];
    const float* b2l = (const float*)d_in[14];
    float* out = (float*)d_out;

    float* AO = (float*)d_ws;                                      // 4MB
    float* X  = AO + (size_t)BN * DIM;                             // 4MB
    unsigned int* adjbT = (unsigned int*)(X + (size_t)BN * DIM);   // 512KB
    __bf16* Qb  = (__bf16*)(adjbT + (size_t)64 * 2048);            // 2MB
    __bf16* Kb  = Qb + (size_t)BN * DIM;                           // 2MB
    __bf16* Vt  = Kb + (size_t)BN * DIM;                           // 2MB
    __bf16* Xb  = Vt + (size_t)BN * DIM;                           // 2MB
    __bf16* hb  = Xb + (size_t)BN * DIM;                           // 2MB
    __bf16* W1t = hb + (size_t)BN * DIM;                           // 64KB
    __bf16* W2t = W1t + (size_t)DIM * FFN_;                        // 64KB
    __bf16* Wqt = W2t + (size_t)DIM * FFN_;                        // 32KB
    __bf16* Wkt = Wqt + (size_t)DIM * DIM;
    __bf16* Wvt = Wkt + (size_t)DIM * DIM;
    __bf16* Wot = Wvt + (size_t)DIM * DIM;

    hipLaunchKernelGGL(k_adjbits, dim3(N_ * N_ / 256), dim3(256), 0, stream, adj, adjbT);
    hipLaunchKernelGGL(k_wcast, dim3(128), dim3(256), 0, stream,
                       W1, W2, Wq, Wk, Wv, Wo, W1t, W2t, Wqt, Wkt, Wvt, Wot);
    hipLaunchKernelGGL(k_hcast, dim3(BN * DIM / (256 * 8)), dim3(256), 0, stream, h, hb);
    hipLaunchKernelGGL(k_qkv, dim3(BN / 32), dim3(256), 0, stream,
                       hb, Wqt, Wkt, Wvt, Qb, Kb, Vt);
    hipLaunchKernelGGL(k_attn, dim3(B_ * NH * (N_ / 32)), dim3(512), 0, stream,
                       Qb, Kb, Vt, adjbT, AO);
    hipLaunchKernelGGL(k_proj_ln, dim3(BN / 32), dim3(256), 0, stream,
                       AO, h, Wot, bo, g1, b1l, X, Xb);
    hipLaunchKernelGGL(k_ffn_ln, dim3(BN / 32), dim3(256), 0, stream,
                       X, Xb, W1t, b1, W2t, b2, g2, b2l, out);
}

// Round 10
// 65.820 us; speedup vs baseline: 3.7372x; 1.0905x over previous
//
#include <hip/hip_runtime.h>

#define B_   4
#define N_   2048
#define DIM  128
#define NH   8
#define HD   16
#define FFN_ 256
#define LN_EPS 1e-5f
#define BN   (B_*N_)
#define LOG2E 1.44269504f

#if __has_builtin(__builtin_amdgcn_exp2f)
#define EXP2(x) __builtin_amdgcn_exp2f(x)
#else
#define EXP2(x) exp2f(x)
#endif

// 1-bit signed extract -> 0 or 0xFFFFFFFF
#if __has_builtin(__builtin_amdgcn_sbfe)
#define SBFE1(w, p) ((unsigned)__builtin_amdgcn_sbfe((int)(w), (p), 1))
#else
#define SBFE1(w, p) ((unsigned)(((int)((w) << (31 - (p)))) >> 31))
#endif

typedef __bf16 bf16x8 __attribute__((ext_vector_type(8)));
typedef short  s16x8  __attribute__((ext_vector_type(8)));
typedef float  f32x16 __attribute__((ext_vector_type(16)));
typedef unsigned int u32x4 __attribute__((ext_vector_type(4)));

template<class T> struct as_short_vec { using type = s16x8; };

template <class T>
__device__ auto mfma_try(T a, T b, f32x16 c, int)
    -> decltype(__builtin_amdgcn_mfma_f32_32x32x16_bf16(a, b, c, 0, 0, 0)) {
  return __builtin_amdgcn_mfma_f32_32x32x16_bf16(a, b, c, 0, 0, 0);
}
template <class T>
__device__ f32x16 mfma_try(T a, T b, f32x16 c, long) {
  return __builtin_amdgcn_mfma_f32_32x32x16_bf16(
      __builtin_bit_cast(typename as_short_vec<T>::type, a),
      __builtin_bit_cast(typename as_short_vec<T>::type, b), c, 0, 0, 0);
}
__device__ __forceinline__ f32x16 mfma_bf(bf16x8 a, bf16x8 b, f32x16 c) {
  return mfma_try(a, b, c, 0);
}

// ---------------- fused prep: adj bits + h cast + weight cast ----------------
// blocks [0,16384): adj (int32 0/1) -> transposed u32 bit table adjbT[kc][q]
// blocks [16384,16896): h -> bf16
// blocks [16896,17024): weights -> bf16, n-major (Q-scale folded into Wqt)
__global__ __launch_bounds__(256) void k_prep(
    const int* __restrict__ adj, const float* __restrict__ h,
    const float* __restrict__ W1, const float* __restrict__ W2,
    const float* __restrict__ Wq, const float* __restrict__ Wk,
    const float* __restrict__ Wv, const float* __restrict__ Wo,
    unsigned int* __restrict__ adjbT, __bf16* __restrict__ hb,
    __bf16* __restrict__ W1t, __bf16* __restrict__ W2t,
    __bf16* __restrict__ Wqt, __bf16* __restrict__ Wkt,
    __bf16* __restrict__ Wvt, __bf16* __restrict__ Wot) {
    const int blk = blockIdx.x;
    const int tid = threadIdx.x;
    if (blk < 16384) {
        long long idx = (long long)blk * 256 + tid;
        int v = adj[idx] != 0;
        unsigned long long m = __ballot(v);
        if ((tid & 63) == 0) {
            int q  = (int)(idx >> 11);
            int kc = ((int)idx & 2047) >> 5;   // even; covers kc, kc+1
            adjbT[(size_t)kc * 2048 + q]       = (unsigned)m;
            adjbT[(size_t)(kc + 1) * 2048 + q] = (unsigned)(m >> 32);
        }
    } else if (blk < 16896) {
        const int g = (blk - 16384) * 256 + tid;    // BN*DIM/8 threads
        const float* src = h + (size_t)g * 8;
        float4 f0 = *(const float4*)src, f1 = *(const float4*)(src + 4);
        bf16x8 v;
        v[0] = (__bf16)f0.x; v[1] = (__bf16)f0.y; v[2] = (__bf16)f0.z; v[3] = (__bf16)f0.w;
        v[4] = (__bf16)f1.x; v[5] = (__bf16)f1.y; v[6] = (__bf16)f1.z; v[7] = (__bf16)f1.w;
        *(bf16x8*)(hb + (size_t)g * 8) = v;
    } else {
        const int g = (blk - 16896) * 256 + tid;    // 32768 threads
        {
            int k = g >> 8, n = g & 255;
            W1t[(size_t)n * 128 + k] = (__bf16)W1[(size_t)k * 256 + n];
        }
        {
            int k = g >> 7, n = g & 127;
            W2t[(size_t)n * 256 + k] = (__bf16)W2[(size_t)k * 128 + n];
        }
        if (g < 16384) {
            int k = g >> 7, n = g & 127;
            size_t s = (size_t)k * 128 + n, d = (size_t)n * 128 + k;
            Wqt[d] = (__bf16)(Wq[s] * (0.25f * LOG2E));
            Wkt[d] = (__bf16)Wk[s];
            Wvt[d] = (__bf16)Wv[s];
            Wot[d] = (__bf16)Wo[s];
        }
    }
}

// ---------------- QKV projection, MFMA ----------------
// grid BN/32 = 256 blocks x 256 thr (4 waves). Wave w -> out cols [w*32,w*32+32).
// Qb,Kb: [B][H][N][HD] bf16 (Q pre-scaled via Wqt); Vt: [B][H][16][N] key-permuted.
__global__ __launch_bounds__(256) void k_qkv(
    const __bf16* __restrict__ hb,
    const __bf16* __restrict__ Wqt, const __bf16* __restrict__ Wkt,
    const __bf16* __restrict__ Wvt,
    __bf16* __restrict__ Qb, __bf16* __restrict__ Kb, __bf16* __restrict__ Vt) {
    const int r0   = blockIdx.x * 32;
    const int tid  = threadIdx.x;
    const int w    = tid >> 6;
    const int lane = tid & 63;
    const int l31  = lane & 31, hi = lane >> 5;

    __shared__ __bf16 Hs[32 * 128];   // XOR-swizzled: byte ^= (row&7)<<4

    for (int i = tid; i < 512; i += 256) {
        int row = i >> 4, u = i & 15;
        bf16x8 v = *(const bf16x8*)(hb + (size_t)(r0 + row) * DIM + u * 8);
        int byte = (row * 256 + u * 16) ^ ((row & 7) << 4);
        *(bf16x8*)((char*)Hs + byte) = v;
    }
    __syncthreads();

    f32x16 aq, ak, av;
    #pragma unroll
    for (int i = 0; i < 16; ++i) { aq[i] = 0.f; ak[i] = 0.f; av[i] = 0.f; }
    #pragma unroll
    for (int kk = 0; kk < 8; ++kk) {
        int byte = (l31 * 256 + kk * 32 + hi * 16) ^ ((l31 & 7) << 4);
        bf16x8 a = *(const bf16x8*)((const char*)Hs + byte);
        const size_t wo = (size_t)(w * 32 + l31) * 128 + kk * 16 + hi * 8;
        aq = mfma_bf(a, *(const bf16x8*)(Wqt + wo), aq);
        ak = mfma_bf(a, *(const bf16x8*)(Wkt + wo), ak);
        av = mfma_bf(a, *(const bf16x8*)(Wvt + wo), av);
    }
    const int n  = w * 32 + l31;           // output col 0..127
    const int hh = n >> 4, d = n & 15;
    const int b  = r0 >> 11;
    const size_t qbase = (size_t)(b * NH + hh) * N_;
    const size_t vbase = ((size_t)(b * NH + hh) * HD + d) * N_;
    #pragma unroll
    for (int r = 0; r < 16; ++r) {
        int mm   = (r & 3) + 8 * (r >> 2) + 4 * hi;
        int nloc = (r0 & (N_ - 1)) + mm;
        size_t qk = (qbase + nloc) * HD + d;
        Qb[qk] = (__bf16)aq[r];
        Kb[qk] = (__bf16)ak[r];
        int gg = (nloc >> 2) & 7;
        int ng = (gg & 4) | ((gg & 1) << 1) | ((gg >> 1) & 1);
        Vt[vbase + ((nloc & ~31) | (ng << 2) | (nloc & 3))] = (__bf16)av[r];
    }
}

// ---------------- masked flash attention, MFMA, fixed-max softmax ----------
// grid: B*H*(N/32) = 2048 blocks x 512 thr (8 waves); wave kq = 256-key eighth.
// XCD-chunked swizzle: blockIdx round-robins over 8 XCDs, so remap gives each
// XCD 256 consecutive work items = 4 whole (b,h) groups -> K/V/Q (768KB) +
// adjbT (512KB) stay L2-resident (r8: FETCH 17.7MB vs 6.5MB ideal was K/V
// re-fetched by all 8 XCDs).
// Fixed max (m=0): st = 0.25*log2e*(Q.K), sigma~0.5 -> |st|>8 is >16-sigma;
// p = 2^st in [2^-8, 2^8]. Split-K merge is a pure sum (sum rides in acc[8]).
// Do NOT pin launch_bounds min-waves above 4 (r5: VGPR=32 forced, acc spilled).
__global__ __launch_bounds__(512, 4) void k_attn(
    const __bf16* __restrict__ Qb, const __bf16* __restrict__ Kb,
    const __bf16* __restrict__ Vt, const unsigned int* __restrict__ adjbT,
    __bf16* __restrict__ AOb) {
    const int bid  = (blockIdx.x & 7) * 256 + (blockIdx.x >> 3);  // XCD chunking
    const int qt   = bid & 63;          // N/32 = 64 q-tiles
    const int hh   = (bid >> 6) & 7;
    const int b    = bid >> 9;
    const int kq   = threadIdx.x >> 6;  // wave = K eighth
    const int lane = threadIdx.x & 63;
    const int l31  = lane & 31, hi = lane >> 5;
    const int q     = qt * 32 + l31;
    const int kbase = kq * 256;
    const int NT    = 8;                // 8 tiles of 32 keys per eighth

    __shared__ float accL[7][64][9];

    const __bf16* Qh = Qb + (size_t)(b * NH + hh) * N_ * HD;
    const __bf16* Kh = Kb + (size_t)(b * NH + hh) * N_ * HD;
    const __bf16* Vh = Vt + ((size_t)(b * NH + hh) * HD + (l31 & 15)) * N_;
    const unsigned int* wp = adjbT + (size_t)(kq * NT) * 2048 + q;
    const bool vload = (l31 < 16);
    const bf16x8 ones8 = __builtin_bit_cast(bf16x8,
        u32x4{0x3F803F80u, 0x3F803F80u, 0x3F803F80u, 0x3F803F80u});

    bf16x8 qf = *(const bf16x8*)(Qh + (size_t)q * HD + hi * 8);

    f32x16 acc;
    #pragma unroll
    for (int i = 0; i < 16; ++i) acc[i] = 0.f;
    const f32x16 z = {};

    bf16x8 kf  = *(const bf16x8*)(Kh + (size_t)(kbase + l31) * HD + hi * 8);
    bf16x8 vfa = vload ? *(const bf16x8*)(Vh + kbase + hi * 8)      : ones8;
    bf16x8 vfb = vload ? *(const bf16x8*)(Vh + kbase + 16 + hi * 8) : ones8;
    unsigned int w32 = wp[0];

    for (int t = 0; t < NT; ++t) {
        // branch-free prefetch of tile t+1 (clamped: last iter re-loads t)
        const int tn = (t + 1 < NT) ? t + 1 : t;
        const int k1 = kbase + tn * 32;
        bf16x8 kf_n = *(const bf16x8*)(Kh + (size_t)(k1 + l31) * HD + hi * 8);
        bf16x8 vfa_n = vload ? *(const bf16x8*)(Vh + k1 + hi * 8)      : ones8;
        bf16x8 vfb_n = vload ? *(const bf16x8*)(Vh + k1 + 16 + hi * 8) : ones8;
        unsigned int w32_n = wp[(size_t)tn * 2048];

        // S^T[k][q] (log2-scaled): D: q = l31, k = (r&3)+8*(r>>2)+4*hi
        f32x16 st = mfma_bf(kf, qf, z);

        // p = 2^st (fixed max), mask applied on packed bf16 via AND
        float p[16];
        #pragma unroll
        for (int r = 0; r < 16; ++r) p[r] = EXP2(st[r]);
        bf16x8 pa, pb;
        #pragma unroll
        for (int r = 0; r < 8; ++r) { pa[r] = (__bf16)p[r]; pb[r] = (__bf16)p[r + 8]; }

        // expand mask bits -> packed-bf16 AND masks (word j of pa covers key
        // positions pj, pj+1 with pj = (2j&3)+8*(2j>>2)+4*hi; pb same +16).
        // (x & 0xFFFF) | (y & ~0xFFFF) matches v_bfi_b32.
        {
            const unsigned ws = w32 >> (4 * hi);
            u32x4 mA, mB;
            #pragma unroll
            for (int j = 0; j < 4; ++j) {
                const int pj = ((2 * j) & 3) + 8 * ((2 * j) >> 2);   // 0,2,8,10
                mA[j] = (SBFE1(ws, pj)      & 0xFFFFu) | (SBFE1(ws, pj + 1)  & 0xFFFF0000u);
                mB[j] = (SBFE1(ws, pj + 16) & 0xFFFFu) | (SBFE1(ws, pj + 17) & 0xFFFF0000u);
            }
            pa = __builtin_bit_cast(bf16x8, __builtin_bit_cast(u32x4, pa) & mA);
            pb = __builtin_bit_cast(bf16x8, __builtin_bit_cast(u32x4, pb) & mB);
        }

        // PV; A rows 16..31 are register-ones -> acc[8] accumulates sum(p)
        acc = mfma_bf(vfa, pa, acc);
        acc = mfma_bf(vfb, pb, acc);

        kf = kf_n; vfa = vfa_n; vfb = vfb_n; w32 = w32_n;
    }

    // ---- 8-way split-K merge: pure sums ----
    if (kq != 0) {
        #pragma unroll
        for (int r = 0; r < 9; ++r) accL[kq - 1][lane][r] = acc[r];
    }
    __syncthreads();
    if (kq == 0) {
        float tot[9];
        #pragma unroll
        for (int r = 0; r < 9; ++r) {
            float v = acc[r];
            #pragma unroll
            for (int i = 0; i < 7; ++i) v += accL[i][lane][r];
            tot[r] = v;
        }
        float inv = 1.f / tot[8];
        bf16x8 ov;
        #pragma unroll
        for (int r = 0; r < 8; ++r) ov[r] = (__bf16)(tot[r] * inv);
        u32x4 ou = __builtin_bit_cast(u32x4, ov);
        __bf16* op = AOb + ((size_t)(b * N_ + q)) * DIM + hh * HD + 4 * hi;
        uint2 w0 = { ou[0], ou[1] }, w1 = { ou[2], ou[3] };
        *(uint2*)op       = w0;   // d = 4*hi + 0..3
        *(uint2*)(op + 8) = w1;   // d = 8 + 4*hi + 0..3
    }
}

// ---------------- Wo projection + residual + LN1, MFMA -> Xb bf16 ----------
// grid BN/32 = 256 blocks x 256 thr.
__global__ __launch_bounds__(256) void k_proj_ln(
    const __bf16* __restrict__ AOb, const float* __restrict__ h,
    const __bf16* __restrict__ Wot, const float* __restrict__ bo,
    const float* __restrict__ g, const float* __restrict__ bln,
    __bf16* __restrict__ Xb) {
    const int r0   = blockIdx.x * 32;
    const int tid  = threadIdx.x;
    const int w    = tid >> 6;
    const int lane = tid & 63;
    const int l31  = lane & 31, hi = lane >> 5;

    __shared__ __bf16 As[32 * 128];   // XOR-swizzled
    __shared__ float  vv[32][DIM];

    for (int i = tid; i < 512; i += 256) {
        int row = i >> 4, u = i & 15;
        bf16x8 v = *(const bf16x8*)(AOb + (size_t)(r0 + row) * DIM + u * 8);
        int byte = (row * 256 + u * 16) ^ ((row & 7) << 4);
        *(bf16x8*)((char*)As + byte) = v;
    }
    __syncthreads();

    f32x16 acc;
    #pragma unroll
    for (int i = 0; i < 16; ++i) acc[i] = 0.f;
    #pragma unroll
    for (int kk = 0; kk < 8; ++kk) {
        int byte = (l31 * 256 + kk * 32 + hi * 16) ^ ((l31 & 7) << 4);
        bf16x8 a = *(const bf16x8*)((const char*)As + byte);
        acc = mfma_bf(a, *(const bf16x8*)(Wot + (size_t)(w * 32 + l31) * 128 + kk * 16 + hi * 8), acc);
    }
    {
        int n = w * 32 + l31;
        float bb = bo[n];
        #pragma unroll
        for (int r = 0; r < 16; ++r) {
            int mm = (r & 3) + 8 * (r >> 2) + 4 * hi;
            vv[mm][n] = acc[r] + bb + h[(size_t)(r0 + mm) * DIM + n];
        }
    }
    __syncthreads();

    const int ln = lane;
    float gc0 = g[ln], bc0 = bln[ln], gc1 = g[ln + 64], bc1 = bln[ln + 64];
    #pragma unroll
    for (int i = 0; i < 8; ++i) {
        int rr = w * 8 + i;
        float x0 = vv[rr][ln], x1 = vv[rr][ln + 64];
        float s = x0 + x1, s2 = x0 * x0 + x1 * x1;
        for (int off = 1; off < 64; off <<= 1) {
            s  += __shfl_xor(s,  off);
            s2 += __shfl_xor(s2, off);
        }
        float mu  = s * (1.f / DIM);
        float var = s2 * (1.f / DIM) - mu * mu;
        float rs  = rsqrtf(var + LN_EPS);
        size_t o = (size_t)(r0 + rr) * DIM;
        Xb[o + ln]      = (__bf16)((x0 - mu) * rs * gc0 + bc0);
        Xb[o + ln + 64] = (__bf16)((x1 - mu) * rs * gc1 + bc1);
    }
}

// ---------------- FFN + residual + LN2, MFMA ----------------
// Residual X re-read from the staged swizzled Xs tile (no fp32 X buffer).
__global__ __launch_bounds__(256) void k_ffn_ln(
    const __bf16* __restrict__ Xb,
    const __bf16* __restrict__ W1t, const float* __restrict__ b1,
    const __bf16* __restrict__ W2t, const float* __restrict__ b2,
    const float* __restrict__ g, const float* __restrict__ bln,
    float* __restrict__ out) {
    const int r0   = blockIdx.x * 32;
    const int tid  = threadIdx.x;
    const int w    = tid >> 6;
    const int lane = tid & 63;
    const int l31  = lane & 31, hi = lane >> 5;

    __shared__ __bf16 Xs[32 * 128];   // XOR-swizzled
    __shared__ __bf16 Ts[32 * 256];   // XOR-swizzled
    __shared__ float  vv[32][DIM];

    for (int i = tid; i < 512; i += 256) {
        int row = i >> 4, u = i & 15;
        bf16x8 v = *(const bf16x8*)(Xb + (size_t)(r0 + row) * DIM + u * 8);
        int byte = (row * 256 + u * 16) ^ ((row & 7) << 4);
        *(bf16x8*)((char*)Xs + byte) = v;
    }
    __syncthreads();

    f32x16 acc1a, acc1b;
    #pragma unroll
    for (int i = 0; i < 16; ++i) { acc1a[i] = 0.f; acc1b[i] = 0.f; }
    #pragma unroll
    for (int kk = 0; kk < 8; ++kk) {
        int byte = (l31 * 256 + kk * 32 + hi * 16) ^ ((l31 & 7) << 4);
        bf16x8 a = *(const bf16x8*)((const char*)Xs + byte);
        bf16x8 bA = *(const bf16x8*)(W1t + (size_t)(w * 32 + l31) * 128 + kk * 16 + hi * 8);
        bf16x8 bB = *(const bf16x8*)(W1t + (size_t)((w + 4) * 32 + l31) * 128 + kk * 16 + hi * 8);
        acc1a = mfma_bf(a, bA, acc1a);
        acc1b = mfma_bf(a, bB, acc1b);
    }
    #pragma unroll
    for (int ct = 0; ct < 2; ++ct) {
        const f32x16& ac = ct ? acc1b : acc1a;
        int n = (w + ct * 4) * 32 + l31;
        float bb = b1[n];
        #pragma unroll
        for (int r = 0; r < 16; ++r) {
            int mm = (r & 3) + 8 * (r >> 2) + 4 * hi;
            float v = fmaxf(ac[r] + bb, 0.f);
            int byte = (mm * 512 + n * 2) ^ ((mm & 7) << 4);
            *(__bf16*)((char*)Ts + byte) = (__bf16)v;
        }
    }
    __syncthreads();

    f32x16 acc2;
    #pragma unroll
    for (int i = 0; i < 16; ++i) acc2[i] = 0.f;
    #pragma unroll
    for (int kk = 0; kk < 16; ++kk) {
        int byte = (l31 * 512 + kk * 32 + hi * 16) ^ ((l31 & 7) << 4);
        bf16x8 a = *(const bf16x8*)((const char*)Ts + byte);
        bf16x8 bb = *(const bf16x8*)(W2t + (size_t)(w * 32 + l31) * 256 + kk * 16 + hi * 8);
        acc2 = mfma_bf(a, bb, acc2);
    }
    {
        int n = w * 32 + l31;
        float bb = b2[n];
        #pragma unroll
        for (int r = 0; r < 16; ++r) {
            int mm = (r & 3) + 8 * (r >> 2) + 4 * hi;
            int byteR = (mm * 256 + n * 2) ^ ((mm & 7) << 4);
            float resid = (float)*(const __bf16*)((const char*)Xs + byteR);
            vv[mm][n] = acc2[r] + bb + resid;
        }
    }
    __syncthreads();

    const int ln = lane;
    float gc0 = g[ln], bc0 = bln[ln], gc1 = g[ln + 64], bc1 = bln[ln + 64];
    #pragma unroll
    for (int i = 0; i < 8; ++i) {
        int rr = w * 8 + i;
        float x0 = vv[rr][ln], x1 = vv[rr][ln + 64];
        float s = x0 + x1, s2 = x0 * x0 + x1 * x1;
        for (int off = 1; off < 64; off <<= 1) {
            s  += __shfl_xor(s,  off);
            s2 += __shfl_xor(s2, off);
        }
        float mu  = s * (1.f / DIM);
        float var = s2 * (1.f / DIM) - mu * mu;
        float rs  = rsqrtf(var + LN_EPS);
        size_t o = (size_t)(r0 + rr) * DIM;
        out[o + ln]      = (x0 - mu) * rs * gc0 + bc0;
        out[o + ln + 64] = (x1 - mu) * rs * gc1 + bc1;
    }
}

extern "C" void kernel_launch(void* const* d_in, const int* in_sizes, int n_in,
                              void* d_out, int out_size, void* d_ws, size_t ws_size,
                              hipStream_t stream) {
    const int*   adj = (const int*)  d_in[0];
    const float* h   = (const float*)d_in[1];
    const float* Wq  = (const float*)d_in[2];
    const float* Wk  = (const float*)d_in[3];
    const float* Wv  = (const float*)d_in[4];
    const float* Wo  = (const float*)d_in[5];
    const float* bo  = (const float*)d_in[6];
    const float* g1  = (const float*)d_in[7];
    const float* b1l = (const float*)d_in[8];
    const float* W1  = (const float*)d_in[9];
    const float* b1  = (const float*)d_in[10];
    const float* W2  = (const float*)d_in[11];
    const float* b2  = (const float*)d_in[12];
    const float* g2  = (const float*)d_in[13];
    const float* b2l = (const float*)d_in[14];
    float* out = (float*)d_out;

    __bf16* AOb = (__bf16*)d_ws;                                   // 2MB
    unsigned int* adjbT = (unsigned int*)(AOb + (size_t)BN * DIM); // 512KB
    __bf16* Qb  = (__bf16*)(adjbT + (size_t)64 * 2048);            // 2MB
    __bf16* Kb  = Qb + (size_t)BN * DIM;                           // 2MB
    __bf16* Vt  = Kb + (size_t)BN * DIM;                           // 2MB
    __bf16* Xb  = Vt + (size_t)BN * DIM;                           // 2MB
    __bf16* hb  = Xb + (size_t)BN * DIM;                           // 2MB
    __bf16* W1t = hb + (size_t)BN * DIM;                           // 64KB
    __bf16* W2t = W1t + (size_t)DIM * FFN_;                        // 64KB
    __bf16* Wqt = W2t + (size_t)DIM * FFN_;                        // 32KB
    __bf16* Wkt = Wqt + (size_t)DIM * DIM;
    __bf16* Wvt = Wkt + (size_t)DIM * DIM;
    __bf16* Wot = Wvt + (size_t)DIM * DIM;

    hipLaunchKernelGGL(k_prep, dim3(16384 + 512 + 128), dim3(256), 0, stream,
                       adj, h, W1, W2, Wq, Wk, Wv, Wo,
                       adjbT, hb, W1t, W2t, Wqt, Wkt, Wvt, Wot);
    hipLaunchKernelGGL(k_qkv, dim3(BN / 32), dim3(256), 0, stream,
                       hb, Wqt, Wkt, Wvt, Qb, Kb, Vt);
    hipLaunchKernelGGL(k_attn, dim3(B_ * NH * (N_ / 32)), dim3(512), 0, stream,
                       Qb, Kb, Vt, adjbT, AOb);
    hipLaunchKernelGGL(k_proj_ln, dim3(BN / 32), dim3(256), 0, stream,
                       AOb, h, Wot, bo, g1, b1l, Xb);
    hipLaunchKernelGGL(k_ffn_ln, dim3(BN / 32), dim3(256), 0, stream,
                       Xb, W1t, b1, W2t, b2, g2, b2l, out);
}

// Round 11
// 63.377 us; speedup vs baseline: 3.8812x; 1.0385x over previous
//
#include <hip/hip_runtime.h>

#define B_   4
#define N_   2048
#define DIM  128
#define NH   8
#define HD   16
#define FFN_ 256
#define LN_EPS 1e-5f
#define BN   (B_*N_)
#define LOG2E 1.44269504f

#if __has_builtin(__builtin_amdgcn_exp2f)
#define EXP2(x) __builtin_amdgcn_exp2f(x)
#else
#define EXP2(x) exp2f(x)
#endif

typedef __bf16 bf16x8 __attribute__((ext_vector_type(8)));
typedef short  s16x8  __attribute__((ext_vector_type(8)));
typedef float  f32x16 __attribute__((ext_vector_type(16)));
typedef unsigned int u32x4 __attribute__((ext_vector_type(4)));

template<class T> struct as_short_vec { using type = s16x8; };

template <class T>
__device__ auto mfma_try(T a, T b, f32x16 c, int)
    -> decltype(__builtin_amdgcn_mfma_f32_32x32x16_bf16(a, b, c, 0, 0, 0)) {
  return __builtin_amdgcn_mfma_f32_32x32x16_bf16(a, b, c, 0, 0, 0);
}
template <class T>
__device__ f32x16 mfma_try(T a, T b, f32x16 c, long) {
  return __builtin_amdgcn_mfma_f32_32x32x16_bf16(
      __builtin_bit_cast(typename as_short_vec<T>::type, a),
      __builtin_bit_cast(typename as_short_vec<T>::type, b), c, 0, 0, 0);
}
__device__ __forceinline__ f32x16 mfma_bf(bf16x8 a, bf16x8 b, f32x16 c) {
  return mfma_try(a, b, c, 0);
}

// ---------------- fused prep: adj bits + weight cast ----------------
// blocks [0,16384): adj (int32 0/1) -> transposed u32 bit table adjbT[kc][q]
// blocks [16384,16512): weights -> bf16, n-major (Q-scale folded into Wqt)
__global__ __launch_bounds__(256) void k_prep(
    const int* __restrict__ adj,
    const float* __restrict__ W1, const float* __restrict__ W2,
    const float* __restrict__ Wq, const float* __restrict__ Wk,
    const float* __restrict__ Wv, const float* __restrict__ Wo,
    unsigned int* __restrict__ adjbT,
    __bf16* __restrict__ W1t, __bf16* __restrict__ W2t,
    __bf16* __restrict__ Wqt, __bf16* __restrict__ Wkt,
    __bf16* __restrict__ Wvt, __bf16* __restrict__ Wot) {
    const int blk = blockIdx.x;
    const int tid = threadIdx.x;
    if (blk < 16384) {
        long long idx = (long long)blk * 256 + tid;
        int v = adj[idx] != 0;
        unsigned long long m = __ballot(v);
        if ((tid & 63) == 0) {
            int q  = (int)(idx >> 11);
            int kc = ((int)idx & 2047) >> 5;   // even; covers kc, kc+1
            adjbT[(size_t)kc * 2048 + q]       = (unsigned)m;
            adjbT[(size_t)(kc + 1) * 2048 + q] = (unsigned)(m >> 32);
        }
    } else {
        const int g = (blk - 16384) * 256 + tid;    // 32768 threads
        {
            int k = g >> 8, n = g & 255;
            W1t[(size_t)n * 128 + k] = (__bf16)W1[(size_t)k * 256 + n];
        }
        {
            int k = g >> 7, n = g & 127;
            W2t[(size_t)n * 256 + k] = (__bf16)W2[(size_t)k * 128 + n];
        }
        if (g < 16384) {
            int k = g >> 7, n = g & 127;
            size_t s = (size_t)k * 128 + n, d = (size_t)n * 128 + k;
            Wqt[d] = (__bf16)(Wq[s] * (0.25f * LOG2E));
            Wkt[d] = (__bf16)Wk[s];
            Wvt[d] = (__bf16)Wv[s];
            Wot[d] = (__bf16)Wo[s];
        }
    }
}

// ---------------- QKV projection, MFMA (h cast in-register) ----------------
// grid BN/32 = 256 blocks x 256 thr (4 waves). Wave w -> out cols [w*32,w*32+32).
// Qb,Kb: [B][H][N][HD] bf16 (Q pre-scaled via Wqt); Vt: [B][H][16][N] key-permuted.
__global__ __launch_bounds__(256) void k_qkv(
    const float* __restrict__ h,
    const __bf16* __restrict__ Wqt, const __bf16* __restrict__ Wkt,
    const __bf16* __restrict__ Wvt,
    __bf16* __restrict__ Qb, __bf16* __restrict__ Kb, __bf16* __restrict__ Vt) {
    const int r0   = blockIdx.x * 32;
    const int tid  = threadIdx.x;
    const int w    = tid >> 6;
    const int lane = tid & 63;
    const int l31  = lane & 31, hi = lane >> 5;

    __shared__ __bf16 Hs[32 * 128];   // XOR-swizzled: byte ^= (row&7)<<4

    for (int i = tid; i < 512; i += 256) {
        int row = i >> 4, u = i & 15;
        const float* src = h + (size_t)(r0 + row) * DIM + u * 8;
        float4 f0 = *(const float4*)src, f1 = *(const float4*)(src + 4);
        bf16x8 v;
        v[0] = (__bf16)f0.x; v[1] = (__bf16)f0.y; v[2] = (__bf16)f0.z; v[3] = (__bf16)f0.w;
        v[4] = (__bf16)f1.x; v[5] = (__bf16)f1.y; v[6] = (__bf16)f1.z; v[7] = (__bf16)f1.w;
        int byte = (row * 256 + u * 16) ^ ((row & 7) << 4);
        *(bf16x8*)((char*)Hs + byte) = v;
    }
    __syncthreads();

    f32x16 aq, ak, av;
    #pragma unroll
    for (int i = 0; i < 16; ++i) { aq[i] = 0.f; ak[i] = 0.f; av[i] = 0.f; }
    #pragma unroll
    for (int kk = 0; kk < 8; ++kk) {
        int byte = (l31 * 256 + kk * 32 + hi * 16) ^ ((l31 & 7) << 4);
        bf16x8 a = *(const bf16x8*)((const char*)Hs + byte);
        const size_t wo = (size_t)(w * 32 + l31) * 128 + kk * 16 + hi * 8;
        aq = mfma_bf(a, *(const bf16x8*)(Wqt + wo), aq);
        ak = mfma_bf(a, *(const bf16x8*)(Wkt + wo), ak);
        av = mfma_bf(a, *(const bf16x8*)(Wvt + wo), av);
    }
    const int n  = w * 32 + l31;           // output col 0..127
    const int hh = n >> 4, d = n & 15;
    const int b  = r0 >> 11;
    const size_t qbase = (size_t)(b * NH + hh) * N_;
    const size_t vbase = ((size_t)(b * NH + hh) * HD + d) * N_;
    #pragma unroll
    for (int r = 0; r < 16; ++r) {
        int mm   = (r & 3) + 8 * (r >> 2) + 4 * hi;
        int nloc = (r0 & (N_ - 1)) + mm;
        size_t qk = (qbase + nloc) * HD + d;
        Qb[qk] = (__bf16)aq[r];
        Kb[qk] = (__bf16)ak[r];
        int gg = (nloc >> 2) & 7;
        int ng = (gg & 4) | ((gg & 1) << 1) | ((gg >> 1) & 1);
        Vt[vbase + ((nloc & ~31) | (ng << 2) | (nloc & 3))] = (__bf16)av[r];
    }
}

// ---------------- masked flash attention, MFMA, fixed-max softmax ----------
// grid: B*H*(N/32) = 2048 blocks x 512 thr (8 waves); wave kq = 256-key eighth.
// XCD-chunked blockIdx swizzle keeps each XCD's 4 (b,h) groups L2-resident.
// Fixed max (m=0): st = 0.25*log2e*(Q.K), sigma~0.5 -> p = 2^st in [2^-8,2^8].
// Mask expansion via 16-entry LDS LUT (nibble -> 2 packed 16-bit AND masks):
// 13 VALU + 4 conflict-free ds_read_b64 per tile, replacing the ~48-op
// SBFE/AND/OR chain (r8-r10). LUT entries cover all 32 banks exactly once.
// Do NOT pin launch_bounds min-waves above 4 (r5: VGPR=32 forced, acc spilled).
__global__ __launch_bounds__(512, 4) void k_attn(
    const __bf16* __restrict__ Qb, const __bf16* __restrict__ Kb,
    const __bf16* __restrict__ Vt, const unsigned int* __restrict__ adjbT,
    __bf16* __restrict__ AOb) {
    const int bid  = (blockIdx.x & 7) * 256 + (blockIdx.x >> 3);  // XCD chunking
    const int qt   = bid & 63;          // N/32 = 64 q-tiles
    const int hh   = (bid >> 6) & 7;
    const int b    = bid >> 9;
    const int kq   = threadIdx.x >> 6;  // wave = K eighth
    const int lane = threadIdx.x & 63;
    const int l31  = lane & 31, hi = lane >> 5;
    const int q     = qt * 32 + l31;
    const int kbase = kq * 256;
    const int NT    = 8;                // 8 tiles of 32 keys per eighth

    __shared__ float accL[7][64][9];
    __shared__ uint2 lutM[16];

    if (threadIdx.x < 16) {
        unsigned v = threadIdx.x;
        lutM[v].x = ((v & 1u) ? 0xFFFFu : 0u) | ((v & 2u) ? 0xFFFF0000u : 0u);
        lutM[v].y = ((v & 4u) ? 0xFFFFu : 0u) | ((v & 8u) ? 0xFFFF0000u : 0u);
    }
    __syncthreads();

    const __bf16* Qh = Qb + (size_t)(b * NH + hh) * N_ * HD;
    const __bf16* Kh = Kb + (size_t)(b * NH + hh) * N_ * HD;
    const __bf16* Vh = Vt + ((size_t)(b * NH + hh) * HD + (l31 & 15)) * N_;
    const unsigned int* wp = adjbT + (size_t)(kq * NT) * 2048 + q;
    const bool vload = (l31 < 16);
    const bf16x8 ones8 = __builtin_bit_cast(bf16x8,
        u32x4{0x3F803F80u, 0x3F803F80u, 0x3F803F80u, 0x3F803F80u});

    bf16x8 qf = *(const bf16x8*)(Qh + (size_t)q * HD + hi * 8);

    f32x16 acc;
    #pragma unroll
    for (int i = 0; i < 16; ++i) acc[i] = 0.f;
    const f32x16 z = {};

    bf16x8 kf  = *(const bf16x8*)(Kh + (size_t)(kbase + l31) * HD + hi * 8);
    bf16x8 vfa = vload ? *(const bf16x8*)(Vh + kbase + hi * 8)      : ones8;
    bf16x8 vfb = vload ? *(const bf16x8*)(Vh + kbase + 16 + hi * 8) : ones8;
    unsigned int w32 = wp[0];

    for (int t = 0; t < NT; ++t) {
        // LUT mask reads issue first: consumed after QK-MFMA + exp chain,
        // so LDS latency is covered.
        const unsigned ws = w32 >> (4 * hi);
        uint2 e0 = lutM[ws & 15u];
        uint2 e1 = lutM[(ws >> 8) & 15u];
        uint2 e2 = lutM[(ws >> 16) & 15u];
        uint2 e3 = lutM[(ws >> 24) & 15u];

        // branch-free prefetch of tile t+1 (clamped: last iter re-loads t)
        const int tn = (t + 1 < NT) ? t + 1 : t;
        const int k1 = kbase + tn * 32;
        bf16x8 kf_n = *(const bf16x8*)(Kh + (size_t)(k1 + l31) * HD + hi * 8);
        bf16x8 vfa_n = vload ? *(const bf16x8*)(Vh + k1 + hi * 8)      : ones8;
        bf16x8 vfb_n = vload ? *(const bf16x8*)(Vh + k1 + 16 + hi * 8) : ones8;
        unsigned int w32_n = wp[(size_t)tn * 2048];

        // S^T[k][q] (log2-scaled): D: q = l31, k = (r&3)+8*(r>>2)+4*hi
        f32x16 st = mfma_bf(kf, qf, z);

        // p = 2^st (fixed max), mask applied on packed bf16 via AND
        float p[16];
        #pragma unroll
        for (int r = 0; r < 16; ++r) p[r] = EXP2(st[r]);
        bf16x8 pa, pb;
        #pragma unroll
        for (int r = 0; r < 8; ++r) { pa[r] = (__bf16)p[r]; pb[r] = (__bf16)p[r + 8]; }

        u32x4 mA = {e0.x, e0.y, e1.x, e1.y};
        u32x4 mB = {e2.x, e2.y, e3.x, e3.y};
        pa = __builtin_bit_cast(bf16x8, __builtin_bit_cast(u32x4, pa) & mA);
        pb = __builtin_bit_cast(bf16x8, __builtin_bit_cast(u32x4, pb) & mB);

        // PV; A rows 16..31 are register-ones -> acc[8] accumulates sum(p)
        acc = mfma_bf(vfa, pa, acc);
        acc = mfma_bf(vfb, pb, acc);

        kf = kf_n; vfa = vfa_n; vfb = vfb_n; w32 = w32_n;
    }

    // ---- 8-way split-K merge: pure sums ----
    if (kq != 0) {
        #pragma unroll
        for (int r = 0; r < 9; ++r) accL[kq - 1][lane][r] = acc[r];
    }
    __syncthreads();
    if (kq == 0) {
        float tot[9];
        #pragma unroll
        for (int r = 0; r < 9; ++r) {
            float v = acc[r];
            #pragma unroll
            for (int i = 0; i < 7; ++i) v += accL[i][lane][r];
            tot[r] = v;
        }
        float inv = 1.f / tot[8];
        bf16x8 ov;
        #pragma unroll
        for (int r = 0; r < 8; ++r) ov[r] = (__bf16)(tot[r] * inv);
        u32x4 ou = __builtin_bit_cast(u32x4, ov);
        __bf16* op = AOb + ((size_t)(b * N_ + q)) * DIM + hh * HD + 4 * hi;
        uint2 w0 = { ou[0], ou[1] }, w1 = { ou[2], ou[3] };
        *(uint2*)op       = w0;   // d = 4*hi + 0..3
        *(uint2*)(op + 8) = w1;   // d = 8 + 4*hi + 0..3
    }
}

// ------- fused tail: Wo proj + residual + LN1 + FFN + residual + LN2 -------
// grid BN/32 = 256 blocks x 256 thr. LN1 output lives only in swizzled LDS.
__global__ __launch_bounds__(256) void k_tail(
    const __bf16* __restrict__ AOb, const float* __restrict__ h,
    const __bf16* __restrict__ Wot, const float* __restrict__ bo,
    const float* __restrict__ g1, const float* __restrict__ b1ln,
    const __bf16* __restrict__ W1t, const float* __restrict__ b1,
    const __bf16* __restrict__ W2t, const float* __restrict__ b2,
    const float* __restrict__ g2, const float* __restrict__ b2ln,
    float* __restrict__ out) {
    const int r0   = blockIdx.x * 32;
    const int tid  = threadIdx.x;
    const int w    = tid >> 6;
    const int lane = tid & 63;
    const int l31  = lane & 31, hi = lane >> 5;

    __shared__ __bf16 As[32 * 128];   // XOR-swizzled AO tile
    __shared__ __bf16 Xs[32 * 128];   // XOR-swizzled LN1 output
    __shared__ __bf16 Ts[32 * 256];   // XOR-swizzled FFN hidden
    __shared__ float  vv[32][DIM];

    // stage AOb swizzled
    for (int i = tid; i < 512; i += 256) {
        int row = i >> 4, u = i & 15;
        bf16x8 v = *(const bf16x8*)(AOb + (size_t)(r0 + row) * DIM + u * 8);
        int byte = (row * 256 + u * 16) ^ ((row & 7) << 4);
        *(bf16x8*)((char*)As + byte) = v;
    }
    __syncthreads();

    // GEMM Wo
    f32x16 acc;
    #pragma unroll
    for (int i = 0; i < 16; ++i) acc[i] = 0.f;
    #pragma unroll
    for (int kk = 0; kk < 8; ++kk) {
        int byte = (l31 * 256 + kk * 32 + hi * 16) ^ ((l31 & 7) << 4);
        bf16x8 a = *(const bf16x8*)((const char*)As + byte);
        acc = mfma_bf(a, *(const bf16x8*)(Wot + (size_t)(w * 32 + l31) * 128 + kk * 16 + hi * 8), acc);
    }
    {
        int n = w * 32 + l31;
        float bb = bo[n];
        #pragma unroll
        for (int r = 0; r < 16; ++r) {
            int mm = (r & 3) + 8 * (r >> 2) + 4 * hi;
            vv[mm][n] = acc[r] + bb + h[(size_t)(r0 + mm) * DIM + n];
        }
    }
    __syncthreads();

    // LN1 -> Xs (swizzled bf16, never to global)
    {
        const int ln = lane;
        float gc0 = g1[ln], bc0 = b1ln[ln], gc1 = g1[ln + 64], bc1 = b1ln[ln + 64];
        #pragma unroll
        for (int i = 0; i < 8; ++i) {
            int rr = w * 8 + i;
            float x0 = vv[rr][ln], x1 = vv[rr][ln + 64];
            float s = x0 + x1, s2 = x0 * x0 + x1 * x1;
            for (int off = 1; off < 64; off <<= 1) {
                s  += __shfl_xor(s,  off);
                s2 += __shfl_xor(s2, off);
            }
            float mu  = s * (1.f / DIM);
            float var = s2 * (1.f / DIM) - mu * mu;
            float rs  = rsqrtf(var + LN_EPS);
            int byte0 = (rr * 256 + ln * 2) ^ ((rr & 7) << 4);
            int byte1 = (rr * 256 + (ln + 64) * 2) ^ ((rr & 7) << 4);
            *(__bf16*)((char*)Xs + byte0) = (__bf16)((x0 - mu) * rs * gc0 + bc0);
            *(__bf16*)((char*)Xs + byte1) = (__bf16)((x1 - mu) * rs * gc1 + bc1);
        }
    }
    __syncthreads();

    // GEMM1: T = relu(X @ W1 + b1)
    f32x16 acc1a, acc1b;
    #pragma unroll
    for (int i = 0; i < 16; ++i) { acc1a[i] = 0.f; acc1b[i] = 0.f; }
    #pragma unroll
    for (int kk = 0; kk < 8; ++kk) {
        int byte = (l31 * 256 + kk * 32 + hi * 16) ^ ((l31 & 7) << 4);
        bf16x8 a = *(const bf16x8*)((const char*)Xs + byte);
        bf16x8 bA = *(const bf16x8*)(W1t + (size_t)(w * 32 + l31) * 128 + kk * 16 + hi * 8);
        bf16x8 bB = *(const bf16x8*)(W1t + (size_t)((w + 4) * 32 + l31) * 128 + kk * 16 + hi * 8);
        acc1a = mfma_bf(a, bA, acc1a);
        acc1b = mfma_bf(a, bB, acc1b);
    }
    #pragma unroll
    for (int ct = 0; ct < 2; ++ct) {
        const f32x16& ac = ct ? acc1b : acc1a;
        int n = (w + ct * 4) * 32 + l31;
        float bb = b1[n];
        #pragma unroll
        for (int r = 0; r < 16; ++r) {
            int mm = (r & 3) + 8 * (r >> 2) + 4 * hi;
            float v = fmaxf(ac[r] + bb, 0.f);
            int byte = (mm * 512 + n * 2) ^ ((mm & 7) << 4);
            *(__bf16*)((char*)Ts + byte) = (__bf16)v;
        }
    }
    __syncthreads();

    // GEMM2: C2 = T @ W2 + residual (from Xs)
    f32x16 acc2;
    #pragma unroll
    for (int i = 0; i < 16; ++i) acc2[i] = 0.f;
    #pragma unroll
    for (int kk = 0; kk < 16; ++kk) {
        int byte = (l31 * 512 + kk * 32 + hi * 16) ^ ((l31 & 7) << 4);
        bf16x8 a = *(const bf16x8*)((const char*)Ts + byte);
        bf16x8 bb = *(const bf16x8*)(W2t + (size_t)(w * 32 + l31) * 256 + kk * 16 + hi * 8);
        acc2 = mfma_bf(a, bb, acc2);
    }
    {
        int n = w * 32 + l31;
        float bb = b2[n];
        #pragma unroll
        for (int r = 0; r < 16; ++r) {
            int mm = (r & 3) + 8 * (r >> 2) + 4 * hi;
            int byteR = (mm * 256 + n * 2) ^ ((mm & 7) << 4);
            float resid = (float)*(const __bf16*)((const char*)Xs + byteR);
            vv[mm][n] = acc2[r] + bb + resid;
        }
    }
    __syncthreads();

    // LN2 -> out
    {
        const int ln = lane;
        float gc0 = g2[ln], bc0 = b2ln[ln], gc1 = g2[ln + 64], bc1 = b2ln[ln + 64];
        #pragma unroll
        for (int i = 0; i < 8; ++i) {
            int rr = w * 8 + i;
            float x0 = vv[rr][ln], x1 = vv[rr][ln + 64];
            float s = x0 + x1, s2 = x0 * x0 + x1 * x1;
            for (int off = 1; off < 64; off <<= 1) {
                s  += __shfl_xor(s,  off);
                s2 += __shfl_xor(s2, off);
            }
            float mu  = s * (1.f / DIM);
            float var = s2 * (1.f / DIM) - mu * mu;
            float rs  = rsqrtf(var + LN_EPS);
            size_t o = (size_t)(r0 + rr) * DIM;
            out[o + ln]      = (x0 - mu) * rs * gc0 + bc0;
            out[o + ln + 64] = (x1 - mu) * rs * gc1 + bc1;
        }
    }
}

extern "C" void kernel_launch(void* const* d_in, const int* in_sizes, int n_in,
                              void* d_out, int out_size, void* d_ws, size_t ws_size,
                              hipStream_t stream) {
    const int*   adj = (const int*)  d_in[0];
    const float* h   = (const float*)d_in[1];
    const float* Wq  = (const float*)d_in[2];
    const float* Wk  = (const float*)d_in[3];
    const float* Wv  = (const float*)d_in[4];
    const float* Wo  = (const float*)d_in[5];
    const float* bo  = (const float*)d_in[6];
    const float* g1  = (const float*)d_in[7];
    const float* b1l = (const float*)d_in[8];
    const float* W1  = (const float*)d_in[9];
    const float* b1  = (const float*)d_in[10];
    const float* W2  = (const float*)d_in[11];
    const float* b2  = (const float*)d_in[12];
    const float* g2  = (const float*)d_in[13];
    const float* b2l = (const float*)d_in[14];
    float* out = (float*)d_out;

    __bf16* AOb = (__bf16*)d_ws;                                   // 2MB
    unsigned int* adjbT = (unsigned int*)(AOb + (size_t)BN * DIM); // 512KB
    __bf16* Qb  = (__bf16*)(adjbT + (size_t)64 * 2048);            // 2MB
    __bf16* Kb  = Qb + (size_t)BN * DIM;                           // 2MB
    __bf16* Vt  = Kb + (size_t)BN * DIM;                           // 2MB
    __bf16* W1t = Vt + (size_t)BN * DIM;                           // 64KB
    __bf16* W2t = W1t + (size_t)DIM * FFN_;                        // 64KB
    __bf16* Wqt = W2t + (size_t)DIM * FFN_;                        // 32KB
    __bf16* Wkt = Wqt + (size_t)DIM * DIM;
    __bf16* Wvt = Wkt + (size_t)DIM * DIM;
    __bf16* Wot = Wvt + (size_t)DIM * DIM;

    hipLaunchKernelGGL(k_prep, dim3(16384 + 128), dim3(256), 0, stream,
                       adj, W1, W2, Wq, Wk, Wv, Wo,
                       adjbT, W1t, W2t, Wqt, Wkt, Wvt, Wot);
    hipLaunchKernelGGL(k_qkv, dim3(BN / 32), dim3(256), 0, stream,
                       h, Wqt, Wkt, Wvt, Qb, Kb, Vt);
    hipLaunchKernelGGL(k_attn, dim3(B_ * NH * (N_ / 32)), dim3(512), 0, stream,
                       Qb, Kb, Vt, adjbT, AOb);
    hipLaunchKernelGGL(k_tail, dim3(BN / 32), dim3(256), 0, stream,
                       AOb, h, Wot, bo, g1, b1l, W1t, b1, W2t, b2, g2, b2l, out);
}

// Round 12
// 59.909 us; speedup vs baseline: 4.1059x; 1.0579x over previous
//
#include <hip/hip_runtime.h>

#define B_   4
#define N_   2048
#define DIM  128
#define NH   8
#define HD   16
#define FFN_ 256
#define LN_EPS 1e-5f
#define BN   (B_*N_)
#define LOG2E 1.44269504f

#if __has_builtin(__builtin_amdgcn_exp2f)
#define EXP2(x) __builtin_amdgcn_exp2f(x)
#else
#define EXP2(x) exp2f(x)
#endif

typedef __bf16 bf16x8 __attribute__((ext_vector_type(8)));
typedef short  s16x8  __attribute__((ext_vector_type(8)));
typedef float  f32x16 __attribute__((ext_vector_type(16)));
typedef unsigned int u32x4 __attribute__((ext_vector_type(4)));

template<class T> struct as_short_vec { using type = s16x8; };

template <class T>
__device__ auto mfma_try(T a, T b, f32x16 c, int)
    -> decltype(__builtin_amdgcn_mfma_f32_32x32x16_bf16(a, b, c, 0, 0, 0)) {
  return __builtin_amdgcn_mfma_f32_32x32x16_bf16(a, b, c, 0, 0, 0);
}
template <class T>
__device__ f32x16 mfma_try(T a, T b, f32x16 c, long) {
  return __builtin_amdgcn_mfma_f32_32x32x16_bf16(
      __builtin_bit_cast(typename as_short_vec<T>::type, a),
      __builtin_bit_cast(typename as_short_vec<T>::type, b), c, 0, 0, 0);
}
__device__ __forceinline__ f32x16 mfma_bf(bf16x8 a, bf16x8 b, f32x16 c) {
  return mfma_try(a, b, c, 0);
}

// ---------------- fused prep: adj bits + weight cast + ones buffer ---------
// blocks [0,16384): adj (int32 0/1) -> transposed u32 bit table adjbT[kc][q]
// blocks [16384,16512): weights -> bf16, n-major (Q-scale folded into Wqt);
//                       also fills the 2080-entry bf16 ones buffer.
__global__ __launch_bounds__(256) void k_prep(
    const int* __restrict__ adj,
    const float* __restrict__ W1, const float* __restrict__ W2,
    const float* __restrict__ Wq, const float* __restrict__ Wk,
    const float* __restrict__ Wv, const float* __restrict__ Wo,
    unsigned int* __restrict__ adjbT,
    __bf16* __restrict__ W1t, __bf16* __restrict__ W2t,
    __bf16* __restrict__ Wqt, __bf16* __restrict__ Wkt,
    __bf16* __restrict__ Wvt, __bf16* __restrict__ Wot,
    __bf16* __restrict__ onesb) {
    const int blk = blockIdx.x;
    const int tid = threadIdx.x;
    if (blk < 16384) {
        long long idx = (long long)blk * 256 + tid;
        int v = adj[idx] != 0;
        unsigned long long m = __ballot(v);
        if ((tid & 63) == 0) {
            int q  = (int)(idx >> 11);
            int kc = ((int)idx & 2047) >> 5;   // even; covers kc, kc+1
            adjbT[(size_t)kc * 2048 + q]       = (unsigned)m;
            adjbT[(size_t)(kc + 1) * 2048 + q] = (unsigned)(m >> 32);
        }
    } else {
        const int g = (blk - 16384) * 256 + tid;    // 32768 threads
        {
            int k = g >> 8, n = g & 255;
            W1t[(size_t)n * 128 + k] = (__bf16)W1[(size_t)k * 256 + n];
        }
        {
            int k = g >> 7, n = g & 127;
            W2t[(size_t)n * 256 + k] = (__bf16)W2[(size_t)k * 128 + n];
        }
        if (g < 16384) {
            int k = g >> 7, n = g & 127;
            size_t s = (size_t)k * 128 + n, d = (size_t)n * 128 + k;
            Wqt[d] = (__bf16)(Wq[s] * (0.25f * LOG2E));
            Wkt[d] = (__bf16)Wk[s];
            Wvt[d] = (__bf16)Wv[s];
            Wot[d] = (__bf16)Wo[s];
        }
        if (g < 2080) onesb[g] = (__bf16)1.0f;
    }
}

// ---------------- QKV projection, MFMA (h cast in-register) ----------------
// grid BN/32 = 256 blocks x 256 thr (4 waves). Wave w -> out cols [w*32,w*32+32).
// Qb,Kb: [B][H][N][HD] bf16 (Q pre-scaled via Wqt); Vt: [B][H][16][N] key-permuted.
__global__ __launch_bounds__(256) void k_qkv(
    const float* __restrict__ h,
    const __bf16* __restrict__ Wqt, const __bf16* __restrict__ Wkt,
    const __bf16* __restrict__ Wvt,
    __bf16* __restrict__ Qb, __bf16* __restrict__ Kb, __bf16* __restrict__ Vt) {
    const int r0   = blockIdx.x * 32;
    const int tid  = threadIdx.x;
    const int w    = tid >> 6;
    const int lane = tid & 63;
    const int l31  = lane & 31, hi = lane >> 5;

    __shared__ __bf16 Hs[32 * 128];   // XOR-swizzled: byte ^= (row&7)<<4

    for (int i = tid; i < 512; i += 256) {
        int row = i >> 4, u = i & 15;
        const float* src = h + (size_t)(r0 + row) * DIM + u * 8;
        float4 f0 = *(const float4*)src, f1 = *(const float4*)(src + 4);
        bf16x8 v;
        v[0] = (__bf16)f0.x; v[1] = (__bf16)f0.y; v[2] = (__bf16)f0.z; v[3] = (__bf16)f0.w;
        v[4] = (__bf16)f1.x; v[5] = (__bf16)f1.y; v[6] = (__bf16)f1.z; v[7] = (__bf16)f1.w;
        int byte = (row * 256 + u * 16) ^ ((row & 7) << 4);
        *(bf16x8*)((char*)Hs + byte) = v;
    }
    __syncthreads();

    f32x16 aq, ak, av;
    #pragma unroll
    for (int i = 0; i < 16; ++i) { aq[i] = 0.f; ak[i] = 0.f; av[i] = 0.f; }
    #pragma unroll
    for (int kk = 0; kk < 8; ++kk) {
        int byte = (l31 * 256 + kk * 32 + hi * 16) ^ ((l31 & 7) << 4);
        bf16x8 a = *(const bf16x8*)((const char*)Hs + byte);
        const size_t wo = (size_t)(w * 32 + l31) * 128 + kk * 16 + hi * 8;
        aq = mfma_bf(a, *(const bf16x8*)(Wqt + wo), aq);
        ak = mfma_bf(a, *(const bf16x8*)(Wkt + wo), ak);
        av = mfma_bf(a, *(const bf16x8*)(Wvt + wo), av);
    }
    const int n  = w * 32 + l31;           // output col 0..127
    const int hh = n >> 4, d = n & 15;
    const int b  = r0 >> 11;
    const size_t qbase = (size_t)(b * NH + hh) * N_;
    const size_t vbase = ((size_t)(b * NH + hh) * HD + d) * N_;
    #pragma unroll
    for (int r = 0; r < 16; ++r) {
        int mm   = (r & 3) + 8 * (r >> 2) + 4 * hi;
        int nloc = (r0 & (N_ - 1)) + mm;
        size_t qk = (qbase + nloc) * HD + d;
        Qb[qk] = (__bf16)aq[r];
        Kb[qk] = (__bf16)ak[r];
        int gg = (nloc >> 2) & 7;
        int ng = (gg & 4) | ((gg & 1) << 1) | ((gg >> 1) & 1);
        Vt[vbase + ((nloc & ~31) | (ng << 2) | (nloc & 3))] = (__bf16)av[r];
    }
}

// ---------------- masked flash attention, MFMA, fixed-max softmax ----------
// grid: B*H*(N/32) = 2048 blocks x 512 thr (8 waves); wave kq = 256-key eighth.
// XCD-chunked blockIdx swizzle keeps each XCD's 4 (b,h) groups L2-resident.
// Fixed max (m=0): st = 0.25*log2e*(Q.K), sigma~0.5 -> p = 2^st in [2^-8,2^8].
// Mask expansion via 16-entry LDS LUT (conflict-free broadcast reads).
// r12: lanes l31>=16 read V from a global ones buffer (no per-tile cndmask);
// NT loop fully unrolled -> prefetch addressing is compile-time offsets.
// Do NOT pin launch_bounds min-waves above 4 (r5: VGPR=32 forced, acc spilled).
__global__ __launch_bounds__(512, 4) void k_attn(
    const __bf16* __restrict__ Qb, const __bf16* __restrict__ Kb,
    const __bf16* __restrict__ Vt, const unsigned int* __restrict__ adjbT,
    const __bf16* __restrict__ onesb,
    __bf16* __restrict__ AOb) {
    const int bid  = (blockIdx.x & 7) * 256 + (blockIdx.x >> 3);  // XCD chunking
    const int qt   = bid & 63;          // N/32 = 64 q-tiles
    const int hh   = (bid >> 6) & 7;
    const int b    = bid >> 9;
    const int kq   = threadIdx.x >> 6;  // wave = K eighth
    const int lane = threadIdx.x & 63;
    const int l31  = lane & 31, hi = lane >> 5;
    const int q     = qt * 32 + l31;
    const int kbase = kq * 256;
    const int NT    = 8;                // 8 tiles of 32 keys per eighth

    __shared__ float accL[7][64][9];
    __shared__ uint2 lutM[16];

    if (threadIdx.x < 16) {
        unsigned v = threadIdx.x;
        lutM[v].x = ((v & 1u) ? 0xFFFFu : 0u) | ((v & 2u) ? 0xFFFF0000u : 0u);
        lutM[v].y = ((v & 4u) ? 0xFFFFu : 0u) | ((v & 8u) ? 0xFFFF0000u : 0u);
    }
    __syncthreads();

    const __bf16* Qh = Qb + (size_t)(b * NH + hh) * N_ * HD;
    // base pointers with lane offsets pre-added; compile-time tile offsets below
    const __bf16* Kp = Kb + (size_t)(b * NH + hh) * N_ * HD
                          + (size_t)(kbase + l31) * HD + hi * 8;
    const __bf16* Vp = ((l31 < 16)
        ? (Vt + ((size_t)(b * NH + hh) * HD + l31) * N_)
        : onesb) + kbase + hi * 8;
    const unsigned int* wp = adjbT + (size_t)(kq * NT) * 2048 + q;

    bf16x8 qf = *(const bf16x8*)(Qh + (size_t)q * HD + hi * 8);

    f32x16 acc;
    #pragma unroll
    for (int i = 0; i < 16; ++i) acc[i] = 0.f;
    const f32x16 z = {};

    bf16x8 kf  = *(const bf16x8*)Kp;
    bf16x8 vfa = *(const bf16x8*)Vp;
    bf16x8 vfb = *(const bf16x8*)(Vp + 16);
    unsigned int w32 = wp[0];

    #pragma unroll
    for (int t = 0; t < NT; ++t) {
        // prefetch tile t+1 (compile-time guard; no copies in final iter)
        bf16x8 kf_n = {}, vfa_n = {}, vfb_n = {};
        unsigned int w32_n = 0;
        if (t + 1 < NT) {
            kf_n  = *(const bf16x8*)(Kp + (t + 1) * 32 * HD);
            vfa_n = *(const bf16x8*)(Vp + (t + 1) * 32);
            vfb_n = *(const bf16x8*)(Vp + (t + 1) * 32 + 16);
            w32_n = wp[(size_t)(t + 1) * 2048];
        }

        // LUT mask reads issue early; consumed after QK-MFMA + exp chain
        const unsigned ws = w32 >> (4 * hi);
        uint2 e0 = lutM[ws & 15u];
        uint2 e1 = lutM[(ws >> 8) & 15u];
        uint2 e2 = lutM[(ws >> 16) & 15u];
        uint2 e3 = lutM[(ws >> 24) & 15u];

        // S^T[k][q] (log2-scaled): D: q = l31, k = (r&3)+8*(r>>2)+4*hi
        f32x16 st = mfma_bf(kf, qf, z);

        // p = 2^st (fixed max), mask applied on packed bf16 via AND
        float p[16];
        #pragma unroll
        for (int r = 0; r < 16; ++r) p[r] = EXP2(st[r]);
        bf16x8 pa, pb;
        #pragma unroll
        for (int r = 0; r < 8; ++r) { pa[r] = (__bf16)p[r]; pb[r] = (__bf16)p[r + 8]; }

        u32x4 mA = {e0.x, e0.y, e1.x, e1.y};
        u32x4 mB = {e2.x, e2.y, e3.x, e3.y};
        pa = __builtin_bit_cast(bf16x8, __builtin_bit_cast(u32x4, pa) & mA);
        pb = __builtin_bit_cast(bf16x8, __builtin_bit_cast(u32x4, pb) & mB);

        // PV; A rows 16..31 read global ones -> acc[8] accumulates sum(p)
        acc = mfma_bf(vfa, pa, acc);
        acc = mfma_bf(vfb, pb, acc);

        if (t + 1 < NT) { kf = kf_n; vfa = vfa_n; vfb = vfb_n; w32 = w32_n; }
    }

    // ---- 8-way split-K merge: pure sums ----
    if (kq != 0) {
        #pragma unroll
        for (int r = 0; r < 9; ++r) accL[kq - 1][lane][r] = acc[r];
    }
    __syncthreads();
    if (kq == 0) {
        float tot[9];
        #pragma unroll
        for (int r = 0; r < 9; ++r) {
            float v = acc[r];
            #pragma unroll
            for (int i = 0; i < 7; ++i) v += accL[i][lane][r];
            tot[r] = v;
        }
        float inv = 1.f / tot[8];
        bf16x8 ov;
        #pragma unroll
        for (int r = 0; r < 8; ++r) ov[r] = (__bf16)(tot[r] * inv);
        u32x4 ou = __builtin_bit_cast(u32x4, ov);
        __bf16* op = AOb + ((size_t)(b * N_ + q)) * DIM + hh * HD + 4 * hi;
        uint2 w0 = { ou[0], ou[1] }, w1 = { ou[2], ou[3] };
        *(uint2*)op       = w0;   // d = 4*hi + 0..3
        *(uint2*)(op + 8) = w1;   // d = 8 + 4*hi + 0..3
    }
}

// ------- fused tail: Wo proj + residual + LN1 + FFN + residual + LN2 -------
// grid BN/32 = 256 blocks x 256 thr. LN1 output lives only in swizzled LDS.
__global__ __launch_bounds__(256) void k_tail(
    const __bf16* __restrict__ AOb, const float* __restrict__ h,
    const __bf16* __restrict__ Wot, const float* __restrict__ bo,
    const float* __restrict__ g1, const float* __restrict__ b1ln,
    const __bf16* __restrict__ W1t, const float* __restrict__ b1,
    const __bf16* __restrict__ W2t, const float* __restrict__ b2,
    const float* __restrict__ g2, const float* __restrict__ b2ln,
    float* __restrict__ out) {
    const int r0   = blockIdx.x * 32;
    const int tid  = threadIdx.x;
    const int w    = tid >> 6;
    const int lane = tid & 63;
    const int l31  = lane & 31, hi = lane >> 5;

    __shared__ __bf16 As[32 * 128];   // XOR-swizzled AO tile
    __shared__ __bf16 Xs[32 * 128];   // XOR-swizzled LN1 output
    __shared__ __bf16 Ts[32 * 256];   // XOR-swizzled FFN hidden
    __shared__ float  vv[32][DIM];

    // stage AOb swizzled
    for (int i = tid; i < 512; i += 256) {
        int row = i >> 4, u = i & 15;
        bf16x8 v = *(const bf16x8*)(AOb + (size_t)(r0 + row) * DIM + u * 8);
        int byte = (row * 256 + u * 16) ^ ((row & 7) << 4);
        *(bf16x8*)((char*)As + byte) = v;
    }
    __syncthreads();

    // GEMM Wo
    f32x16 acc;
    #pragma unroll
    for (int i = 0; i < 16; ++i) acc[i] = 0.f;
    #pragma unroll
    for (int kk = 0; kk < 8; ++kk) {
        int byte = (l31 * 256 + kk * 32 + hi * 16) ^ ((l31 & 7) << 4);
        bf16x8 a = *(const bf16x8*)((const char*)As + byte);
        acc = mfma_bf(a, *(const bf16x8*)(Wot + (size_t)(w * 32 + l31) * 128 + kk * 16 + hi * 8), acc);
    }
    {
        int n = w * 32 + l31;
        float bb = bo[n];
        #pragma unroll
        for (int r = 0; r < 16; ++r) {
            int mm = (r & 3) + 8 * (r >> 2) + 4 * hi;
            vv[mm][n] = acc[r] + bb + h[(size_t)(r0 + mm) * DIM + n];
        }
    }
    __syncthreads();

    // LN1 -> Xs (swizzled bf16, never to global)
    {
        const int ln = lane;
        float gc0 = g1[ln], bc0 = b1ln[ln], gc1 = g1[ln + 64], bc1 = b1ln[ln + 64];
        #pragma unroll
        for (int i = 0; i < 8; ++i) {
            int rr = w * 8 + i;
            float x0 = vv[rr][ln], x1 = vv[rr][ln + 64];
            float s = x0 + x1, s2 = x0 * x0 + x1 * x1;
            for (int off = 1; off < 64; off <<= 1) {
                s  += __shfl_xor(s,  off);
                s2 += __shfl_xor(s2, off);
            }
            float mu  = s * (1.f / DIM);
            float var = s2 * (1.f / DIM) - mu * mu;
            float rs  = rsqrtf(var + LN_EPS);
            int byte0 = (rr * 256 + ln * 2) ^ ((rr & 7) << 4);
            int byte1 = (rr * 256 + (ln + 64) * 2) ^ ((rr & 7) << 4);
            *(__bf16*)((char*)Xs + byte0) = (__bf16)((x0 - mu) * rs * gc0 + bc0);
            *(__bf16*)((char*)Xs + byte1) = (__bf16)((x1 - mu) * rs * gc1 + bc1);
        }
    }
    __syncthreads();

    // GEMM1: T = relu(X @ W1 + b1)
    f32x16 acc1a, acc1b;
    #pragma unroll
    for (int i = 0; i < 16; ++i) { acc1a[i] = 0.f; acc1b[i] = 0.f; }
    #pragma unroll
    for (int kk = 0; kk < 8; ++kk) {
        int byte = (l31 * 256 + kk * 32 + hi * 16) ^ ((l31 & 7) << 4);
        bf16x8 a = *(const bf16x8*)((const char*)Xs + byte);
        bf16x8 bA = *(const bf16x8*)(W1t + (size_t)(w * 32 + l31) * 128 + kk * 16 + hi * 8);
        bf16x8 bB = *(const bf16x8*)(W1t + (size_t)((w + 4) * 32 + l31) * 128 + kk * 16 + hi * 8);
        acc1a = mfma_bf(a, bA, acc1a);
        acc1b = mfma_bf(a, bB, acc1b);
    }
    #pragma unroll
    for (int ct = 0; ct < 2; ++ct) {
        const f32x16& ac = ct ? acc1b : acc1a;
        int n = (w + ct * 4) * 32 + l31;
        float bb = b1[n];
        #pragma unroll
        for (int r = 0; r < 16; ++r) {
            int mm = (r & 3) + 8 * (r >> 2) + 4 * hi;
            float v = fmaxf(ac[r] + bb, 0.f);
            int byte = (mm * 512 + n * 2) ^ ((mm & 7) << 4);
            *(__bf16*)((char*)Ts + byte) = (__bf16)v;
        }
    }
    __syncthreads();

    // GEMM2: C2 = T @ W2 + residual (from Xs)
    f32x16 acc2;
    #pragma unroll
    for (int i = 0; i < 16; ++i) acc2[i] = 0.f;
    #pragma unroll
    for (int kk = 0; kk < 16; ++kk) {
        int byte = (l31 * 512 + kk * 32 + hi * 16) ^ ((l31 & 7) << 4);
        bf16x8 a = *(const bf16x8*)((const char*)Ts + byte);
        bf16x8 bb = *(const bf16x8*)(W2t + (size_t)(w * 32 + l31) * 256 + kk * 16 + hi * 8);
        acc2 = mfma_bf(a, bb, acc2);
    }
    {
        int n = w * 32 + l31;
        float bb = b2[n];
        #pragma unroll
        for (int r = 0; r < 16; ++r) {
            int mm = (r & 3) + 8 * (r >> 2) + 4 * hi;
            int byteR = (mm * 256 + n * 2) ^ ((mm & 7) << 4);
            float resid = (float)*(const __bf16*)((const char*)Xs + byteR);
            vv[mm][n] = acc2[r] + bb + resid;
        }
    }
    __syncthreads();

    // LN2 -> out
    {
        const int ln = lane;
        float gc0 = g2[ln], bc0 = b2ln[ln], gc1 = g2[ln + 64], bc1 = b2ln[ln + 64];
        #pragma unroll
        for (int i = 0; i < 8; ++i) {
            int rr = w * 8 + i;
            float x0 = vv[rr][ln], x1 = vv[rr][ln + 64];
            float s = x0 + x1, s2 = x0 * x0 + x1 * x1;
            for (int off = 1; off < 64; off <<= 1) {
                s  += __shfl_xor(s,  off);
                s2 += __shfl_xor(s2, off);
            }
            float mu  = s * (1.f / DIM);
            float var = s2 * (1.f / DIM) - mu * mu;
            float rs  = rsqrtf(var + LN_EPS);
            size_t o = (size_t)(r0 + rr) * DIM;
            out[o + ln]      = (x0 - mu) * rs * gc0 + bc0;
            out[o + ln + 64] = (x1 - mu) * rs * gc1 + bc1;
        }
    }
}

extern "C" void kernel_launch(void* const* d_in, const int* in_sizes, int n_in,
                              void* d_out, int out_size, void* d_ws, size_t ws_size,
                              hipStream_t stream) {
    const int*   adj = (const int*)  d_in[0];
    const float* h   = (const float*)d_in[1];
    const float* Wq  = (const float*)d_in[2];
    const float* Wk  = (const float*)d_in[3];
    const float* Wv  = (const float*)d_in[4];
    const float* Wo  = (const float*)d_in[5];
    const float* bo  = (const float*)d_in[6];
    const float* g1  = (const float*)d_in[7];
    const float* b1l = (const float*)d_in[8];
    const float* W1  = (const float*)d_in[9];
    const float* b1  = (const float*)d_in[10];
    const float* W2  = (const float*)d_in[11];
    const float* b2  = (const float*)d_in[12];
    const float* g2  = (const float*)d_in[13];
    const float* b2l = (const float*)d_in[14];
    float* out = (float*)d_out;

    __bf16* AOb = (__bf16*)d_ws;                                   // 2MB
    unsigned int* adjbT = (unsigned int*)(AOb + (size_t)BN * DIM); // 512KB
    __bf16* Qb  = (__bf16*)(adjbT + (size_t)64 * 2048);            // 2MB
    __bf16* Kb  = Qb + (size_t)BN * DIM;                           // 2MB
    __bf16* Vt  = Kb + (size_t)BN * DIM;                           // 2MB
    __bf16* W1t = Vt + (size_t)BN * DIM;                           // 64KB
    __bf16* W2t = W1t + (size_t)DIM * FFN_;                        // 64KB
    __bf16* Wqt = W2t + (size_t)DIM * FFN_;                        // 32KB
    __bf16* Wkt = Wqt + (size_t)DIM * DIM;
    __bf16* Wvt = Wkt + (size_t)DIM * DIM;
    __bf16* Wot = Wvt + (size_t)DIM * DIM;
    __bf16* onesb = Wot + (size_t)DIM * DIM;                       // 2080 bf16

    hipLaunchKernelGGL(k_prep, dim3(16384 + 128), dim3(256), 0, stream,
                       adj, W1, W2, Wq, Wk, Wv, Wo,
                       adjbT, W1t, W2t, Wqt, Wkt, Wvt, Wot, onesb);
    hipLaunchKernelGGL(k_qkv, dim3(BN / 32), dim3(256), 0, stream,
                       h, Wqt, Wkt, Wvt, Qb, Kb, Vt);
    hipLaunchKernelGGL(k_attn, dim3(B_ * NH * (N_ / 32)), dim3(512), 0, stream,
                       Qb, Kb, Vt, adjbT, onesb, AOb);
    hipLaunchKernelGGL(k_tail, dim3(BN / 32), dim3(256), 0, stream,
                       AOb, h, Wot, bo, g1, b1l, W1t, b1, W2t, b2, g2, b2l, out);
}